// Round 1
// baseline (504.712 us; speedup 1.0000x reference)
//
#include <hip/hip_runtime.h>
#include <math.h>

typedef unsigned short u16;
typedef unsigned char u8;
typedef __attribute__((ext_vector_type(4))) float f32x4;
typedef __attribute__((ext_vector_type(8))) short s16x8;
typedef __attribute__((ext_vector_type(4))) short s16x4;

__device__ __forceinline__ u16 f2bf(float f) {
  unsigned u = __builtin_bit_cast(unsigned, f);
  u += 0x7fffu + ((u >> 16) & 1u);
  return (u16)(u >> 16);
}

#define GLDS16(g, l) __builtin_amdgcn_global_load_lds( \
    (const __attribute__((address_space(1))) void*)(g), \
    (__attribute__((address_space(3))) void*)(l), 16, 0, 0)

// ---------------- GEMM: C[M,N] = A[M,K](bf16) @ BT[N,K](bf16)^T ----------------
// EPI 0: outB = bf16(acc)
// EPI 1: outB = bf16(relu(acc + bias[n]))
// EPI 2: outF = acc + bias[n] + resid[m*N+n]
template <int EPI>
__global__ __launch_bounds__(256, 2) void gemm_bt(
    const u16* __restrict__ A, const u16* __restrict__ BT, int M, int N, int K,
    const float* __restrict__ bias, const float* __restrict__ resid,
    u16* __restrict__ outB, float* __restrict__ outF) {
  __shared__ __align__(16) u16 lA[128 * 32];
  __shared__ __align__(16) u16 lB[128 * 32];
  const int tid = threadIdx.x;
  const int wave = __builtin_amdgcn_readfirstlane(tid >> 6);
  const int lane = tid & 63;
  const int l15 = lane & 15, l4 = lane >> 4;
  const int wr = wave >> 1, wc = wave & 1;
  const int row0 = blockIdx.y * 128, col0 = blockIdx.x * 128;

  f32x4 acc[4][4] = {};

  for (int k0 = 0; k0 < K; k0 += 32) {
#pragma unroll
    for (int c = 0; c < 2; ++c) {
      const int idx = (c * 4 + wave) * 64 + lane;  // 16B-unit index 0..511
      const int r = idx >> 2, cb = (idx & 3) * 8;
      GLDS16(A + (size_t)(row0 + r) * K + k0 + cb, lA + (size_t)(c * 4 + wave) * 512);
      GLDS16(BT + (size_t)(col0 + r) * K + k0 + cb, lB + (size_t)(c * 4 + wave) * 512);
    }
    __syncthreads();
    s16x8 af[4], bfr[4];
#pragma unroll
    for (int m = 0; m < 4; ++m)
      af[m] = *(const s16x8*)&lA[(wr * 64 + m * 16 + l15) * 32 + l4 * 8];
#pragma unroll
    for (int n = 0; n < 4; ++n)
      bfr[n] = *(const s16x8*)&lB[(wc * 64 + n * 16 + l15) * 32 + l4 * 8];
#pragma unroll
    for (int m = 0; m < 4; ++m)
#pragma unroll
      for (int n = 0; n < 4; ++n)
        acc[m][n] = __builtin_amdgcn_mfma_f32_16x16x32_bf16(af[m], bfr[n], acc[m][n], 0, 0, 0);
    __syncthreads();
  }

#pragma unroll
  for (int m = 0; m < 4; ++m) {
    const int rowb = row0 + wr * 64 + m * 16 + l4 * 4;
#pragma unroll
    for (int n = 0; n < 4; ++n) {
      const int col = col0 + wc * 64 + n * 16 + l15;
#pragma unroll
      for (int j = 0; j < 4; ++j) {
        const int r = rowb + j;
        float v = acc[m][n][j];
        if (EPI == 0) {
          outB[(size_t)r * N + col] = f2bf(v);
        } else if (EPI == 1) {
          v += bias[col];
          outB[(size_t)r * N + col] = f2bf(v > 0.0f ? v : 0.0f);
        } else {
          v += bias[col] + resid[(size_t)r * N + col];
          outF[(size_t)r * N + col] = v;
        }
      }
    }
  }
}

// ---------------- weight transpose f32 -> bf16: out[c][r] = bf16(in[r][c]) ----------------
__global__ __launch_bounds__(256) void transpose_f32_bf16(
    const float* __restrict__ in, u16* __restrict__ out, int R, int C) {
  __shared__ float t[32][33];
  const int c0 = blockIdx.x * 32, r0 = blockIdx.y * 32;
  const int tx = threadIdx.x & 31, ty = threadIdx.x >> 5;  // ty 0..7
#pragma unroll
  for (int i = 0; i < 4; ++i)
    t[ty + i * 8][tx] = in[(size_t)(r0 + ty + i * 8) * C + c0 + tx];
  __syncthreads();
#pragma unroll
  for (int i = 0; i < 4; ++i)
    out[(size_t)(c0 + ty + i * 8) * R + r0 + tx] = f2bf(t[tx][ty + i * 8]);
}

// ---------------- batched bf16 transpose: out[b][c][r] = in[b][r][c] ----------------
__global__ __launch_bounds__(256) void transpose_bf16_b(
    const u16* __restrict__ in, u16* __restrict__ out, int R, int C) {
  __shared__ u16 t[32][34];
  const int b = blockIdx.z;
  const u16* pi = in + (size_t)b * R * C;
  u16* po = out + (size_t)b * R * C;
  const int c0 = blockIdx.x * 32, r0 = blockIdx.y * 32;
  const int tx = threadIdx.x & 31, ty = threadIdx.x >> 5;
#pragma unroll
  for (int i = 0; i < 4; ++i)
    t[ty + i * 8][tx] = pi[(size_t)(r0 + ty + i * 8) * C + c0 + tx];
  __syncthreads();
#pragma unroll
  for (int i = 0; i < 4; ++i)
    po[(size_t)(c0 + ty + i * 8) * R + r0 + tx] = t[tx][ty + i * 8];
}

// ---------------- f32 -> bf16 elementwise ----------------
__global__ __launch_bounds__(256) void cvt_f32_bf16(
    const float* __restrict__ in, u16* __restrict__ out, int n4) {
  const int i = blockIdx.x * 256 + threadIdx.x;
  if (i >= n4) return;
  f32x4 v = *(const f32x4*)&in[(size_t)i * 4];
  s16x4 o;
#pragma unroll
  for (int j = 0; j < 4; ++j) o[j] = (short)f2bf(v[j]);
  *(s16x4*)&out[(size_t)i * 4] = o;
}

// ---------------- LayerNorm over D=1024; WB: also write bf16 copy ----------------
template <int WB>
__global__ __launch_bounds__(256) void layernorm_k(
    const float* __restrict__ in, const float* __restrict__ gm, const float* __restrict__ bt,
    float* __restrict__ outF, u16* __restrict__ outB) {
  const int row = blockIdx.x;
  const int t = threadIdx.x;
  const float* xr = in + (size_t)row * 1024;
  f32x4 v = *(const f32x4*)&xr[t * 4];
  float s = v[0] + v[1] + v[2] + v[3];
  float s2 = v[0] * v[0] + v[1] * v[1] + v[2] * v[2] + v[3] * v[3];
#pragma unroll
  for (int o = 32; o; o >>= 1) {
    s += __shfl_down(s, o);
    s2 += __shfl_down(s2, o);
  }
  __shared__ float red[8];
  const int lane = t & 63, wv = t >> 6;
  if (lane == 0) { red[wv] = s; red[4 + wv] = s2; }
  __syncthreads();
  s = red[0] + red[1] + red[2] + red[3];
  s2 = red[4] + red[5] + red[6] + red[7];
  const float mu = s * (1.0f / 1024.0f);
  const float var = fmaxf(s2 * (1.0f / 1024.0f) - mu * mu, 0.0f);
  const float rs = rsqrtf(var + 1e-5f);
  f32x4 g4 = *(const f32x4*)&gm[t * 4];
  f32x4 b4 = *(const f32x4*)&bt[t * 4];
  f32x4 ov;
#pragma unroll
  for (int j = 0; j < 4; ++j) ov[j] = (v[j] - mu) * rs * g4[j] + b4[j];
  *(f32x4*)&outF[(size_t)row * 1024 + t * 4] = ov;
  if (WB) {
    s16x4 ob;
#pragma unroll
    for (int j = 0; j < 4; ++j) ob[j] = (short)f2bf(ov[j]);
    *(s16x4*)&outB[(size_t)row * 1024 + t * 4] = ob;
  }
}

// ---------------- flash attention ----------------
// grid (S/64, B*H), 256 threads = 4 waves; wave handles 16 q rows.
// Q,K: [B*S, 1024] bf16 (head h at cols h*64..). VT: [B*H, 64, S] bf16. mask: [B,S,S] u8.
__global__ __launch_bounds__(256) void attn_k(
    const u16* __restrict__ Q, const u16* __restrict__ Kb, const u16* __restrict__ VT,
    const u8* __restrict__ mask, u16* __restrict__ out) {
  const int S = 2048, Dm = 1024;
  const int bh = blockIdx.y, b = bh >> 4, h = bh & 15;
  const int wave = threadIdx.x >> 6, lane = threadIdx.x & 63;
  const int l15 = lane & 15, l4 = lane >> 4;
  const int q0 = blockIdx.x * 64 + wave * 16;
  __shared__ __align__(16) u16 pl[4][512];

  const size_t qoff = (size_t)(b * S + q0 + l15) * Dm + h * 64;
  const s16x8 qa0 = *(const s16x8*)&Q[qoff + l4 * 8];
  const s16x8 qa1 = *(const s16x8*)&Q[qoff + 32 + l4 * 8];

  f32x4 o[4] = {};
  float mr[4], lr[4];
#pragma unroll
  for (int j = 0; j < 4; ++j) { mr[j] = -1e30f; lr[j] = 0.0f; }

  const u8* mb = mask + (size_t)b * S * S;
  u16* pw = &pl[wave][0];

  for (int kv = 0; kv < S; kv += 32) {
    f32x4 sc[2];
#pragma unroll
    for (int t = 0; t < 2; ++t) {
      const size_t koff = (size_t)(b * S + kv + t * 16 + l15) * Dm + h * 64;
      const s16x8 kf0 = *(const s16x8*)&Kb[koff + l4 * 8];
      const s16x8 kf1 = *(const s16x8*)&Kb[koff + 32 + l4 * 8];
      f32x4 z = {};
      z = __builtin_amdgcn_mfma_f32_16x16x32_bf16(qa0, kf0, z, 0, 0, 0);
      z = __builtin_amdgcn_mfma_f32_16x16x32_bf16(qa1, kf1, z, 0, 0, 0);
      sc[t] = z;
    }
#pragma unroll
    for (int t = 0; t < 2; ++t)
#pragma unroll
      for (int j = 0; j < 4; ++j) {
        float v = sc[t][j] * 0.125f;  // 1/sqrt(64)
        if (mb[(size_t)(q0 + l4 * 4 + j) * S + kv + t * 16 + l15]) v = -INFINITY;
        sc[t][j] = v;
      }
    float al[4];
#pragma unroll
    for (int j = 0; j < 4; ++j) {
      float pm = fmaxf(sc[0][j], sc[1][j]);
#pragma unroll
      for (int w = 1; w < 16; w <<= 1) pm = fmaxf(pm, __shfl_xor(pm, w, 16));
      const float mn = fmaxf(mr[j], pm);
      al[j] = __expf(mr[j] - mn);
      mr[j] = mn;
      const float p0 = __expf(sc[0][j] - mn);
      const float p1 = __expf(sc[1][j] - mn);
      sc[0][j] = p0;
      sc[1][j] = p1;
      float rsum = p0 + p1;
#pragma unroll
      for (int w = 1; w < 16; w <<= 1) rsum += __shfl_xor(rsum, w, 16);
      lr[j] = lr[j] * al[j] + rsum;
    }
#pragma unroll
    for (int n = 0; n < 4; ++n)
#pragma unroll
      for (int j = 0; j < 4; ++j) o[n][j] *= al[j];
    // P (16x32) -> LDS in row-major [16][32]
#pragma unroll
    for (int t = 0; t < 2; ++t)
#pragma unroll
      for (int j = 0; j < 4; ++j)
        pw[(l4 * 4 + j) * 32 + t * 16 + l15] = f2bf(sc[t][j]);
    __syncthreads();
    const s16x8 pa = *(const s16x8*)&pw[l15 * 32 + l4 * 8];
#pragma unroll
    for (int n = 0; n < 4; ++n) {
      const s16x8 vb = *(const s16x8*)&VT[((size_t)bh * 64 + n * 16 + l15) * S + kv + l4 * 8];
      o[n] = __builtin_amdgcn_mfma_f32_16x16x32_bf16(pa, vb, o[n], 0, 0, 0);
    }
    __syncthreads();
  }
#pragma unroll
  for (int j = 0; j < 4; ++j) {
    const float inv = lr[j] > 0.0f ? 1.0f / lr[j] : 0.0f;
    const size_t ooff = (size_t)(b * S + q0 + l4 * 4 + j) * Dm + h * 64;
#pragma unroll
    for (int n = 0; n < 4; ++n) out[ooff + n * 16 + l15] = f2bf(o[n][j] * inv);
  }
}

extern "C" void kernel_launch(void* const* d_in, const int* in_sizes, int n_in,
                              void* d_out, int out_size, void* d_ws, size_t ws_size,
                              hipStream_t stream) {
  (void)in_sizes; (void)n_in; (void)out_size; (void)ws_size;
  const float* x = (const float*)d_in[0];
  const u8* mask = (const u8*)d_in[1];
  const float* Wq = (const float*)d_in[2];
  const float* Wk = (const float*)d_in[3];
  const float* Wv = (const float*)d_in[4];
  const float* Wo = (const float*)d_in[5];
  const float* bo = (const float*)d_in[6];
  const float* W1 = (const float*)d_in[7];
  const float* b1 = (const float*)d_in[8];
  const float* W2 = (const float*)d_in[9];
  const float* b2 = (const float*)d_in[10];
  const float* g1 = (const float*)d_in[11];
  const float* be1 = (const float*)d_in[12];
  const float* g2 = (const float*)d_in[13];
  const float* be2 = (const float*)d_in[14];
  float* outp = (float*)d_out;

  const int B = 2, S = 2048, D = 1024, FF = 4096;
  const int M = B * S;  // 4096
  char* w = (char*)d_ws;
  const size_t MB = 1024 * 1024;
  // static workspace layout (peak 104 MB)
  u16* wqT = (u16*)(w + 0 * MB);      // [1024,1024] bf16   [0,2)
  u16* wkT = (u16*)(w + 2 * MB);      //                    [2,4)
  u16* wvT = (u16*)(w + 4 * MB);      //                    [4,6)
  u16* woT = (u16*)(w + 6 * MB);      //                    [6,8)
  u16* w1T = (u16*)(w + 8 * MB);      // [4096,1024] bf16   [8,16)
  u16* w2T = (u16*)(w + 16 * MB);     // [1024,4096] bf16   [16,24)
  u16* xb  = (u16*)(w + 24 * MB);     // [4096,1024] bf16   [24,32)
  u16* qb  = (u16*)(w + 32 * MB);     //                    [32,40)
  u16* kb  = (u16*)(w + 40 * MB);     //                    [40,48)
  u16* vb  = (u16*)(w + 48 * MB);     //                    [48,56)
  u16* vt  = (u16*)(w + 56 * MB);     // [B*H,64,S] bf16    [56,64)
  float* x0f = (float*)(w + 64 * MB); // [4096,1024] f32    [64,80)
  float* x1f = (float*)(w + 80 * MB); //                    [80,96)
  u16* x1b = (u16*)(w + 96 * MB);     // [4096,1024] bf16   [96,104)
  u16* attn_o = vb;                   // reuse v after transpose
  u16* ff1 = (u16*)(w + 24 * MB);     // [4096,4096] bf16, reuses xb/qb/kb/vb [24,56)
  float* y0f = x0f;                   // reuse x0f after LN1

  // weight prep
  transpose_f32_bf16<<<dim3(32, 32), 256, 0, stream>>>(Wq, wqT, 1024, 1024);
  transpose_f32_bf16<<<dim3(32, 32), 256, 0, stream>>>(Wk, wkT, 1024, 1024);
  transpose_f32_bf16<<<dim3(32, 32), 256, 0, stream>>>(Wv, wvT, 1024, 1024);
  transpose_f32_bf16<<<dim3(32, 32), 256, 0, stream>>>(Wo, woT, 1024, 1024);
  transpose_f32_bf16<<<dim3(128, 32), 256, 0, stream>>>(W1, w1T, 1024, 4096);
  transpose_f32_bf16<<<dim3(32, 128), 256, 0, stream>>>(W2, w2T, 4096, 1024);
  cvt_f32_bf16<<<dim3(M * D / 4 / 256), 256, 0, stream>>>(x, xb, M * D / 4);

  // QKV projections
  gemm_bt<0><<<dim3(D / 128, M / 128), 256, 0, stream>>>(xb, wqT, M, D, D, nullptr, nullptr, qb, nullptr);
  gemm_bt<0><<<dim3(D / 128, M / 128), 256, 0, stream>>>(xb, wkT, M, D, D, nullptr, nullptr, kb, nullptr);
  gemm_bt<0><<<dim3(D / 128, M / 128), 256, 0, stream>>>(xb, wvT, M, D, D, nullptr, nullptr, vb, nullptr);
  // V -> V^T per batch ([S,1024] -> [1024,S])
  transpose_bf16_b<<<dim3(32, 64, 2), 256, 0, stream>>>(vb, vt, 2048, 1024);

  // attention
  attn_k<<<dim3(S / 64, 32), 256, 0, stream>>>(qb, kb, vt, mask, attn_o);

  // Wo projection + bias + residual(x)  -> x0f (f32)
  gemm_bt<2><<<dim3(D / 128, M / 128), 256, 0, stream>>>(attn_o, woT, M, D, D, bo, x, nullptr, x0f);
  // LN1 -> x1f (f32) + x1b (bf16)
  layernorm_k<1><<<dim3(M), 256, 0, stream>>>(x0f, g1, be1, x1f, x1b);
  // FFN1: relu(x1 @ W1 + b1) -> ff1 (bf16)
  gemm_bt<1><<<dim3(FF / 128, M / 128), 256, 0, stream>>>(x1b, w1T, M, FF, D, b1, nullptr, ff1, nullptr);
  // FFN2 + bias + residual(x1) -> y0f (f32)
  gemm_bt<2><<<dim3(D / 128, M / 128), 256, 0, stream>>>(ff1, w2T, M, D, FF, b2, x1f, nullptr, y0f);
  // LN2 -> out (f32)
  layernorm_k<0><<<dim3(M), 256, 0, stream>>>(y0f, g2, be2, outp, nullptr);
}

// Round 2
// 494.269 us; speedup vs baseline: 1.0211x; 1.0211x over previous
//
#include <hip/hip_runtime.h>
#include <math.h>

typedef unsigned short u16;
typedef unsigned char u8;
typedef unsigned int u32;
typedef __attribute__((ext_vector_type(4))) float f32x4;
typedef __attribute__((ext_vector_type(8))) short s16x8;
typedef __attribute__((ext_vector_type(4))) short s16x4;
typedef __attribute__((ext_vector_type(4))) u32 u32x4;

__device__ __forceinline__ u16 f2bf(float f) {
  unsigned u = __builtin_bit_cast(unsigned, f);
  u += 0x7fffu + ((u >> 16) & 1u);
  return (u16)(u >> 16);
}

#define GLDS16(g, l) __builtin_amdgcn_global_load_lds( \
    (const __attribute__((address_space(1))) void*)(g), \
    (__attribute__((address_space(3))) void*)(l), 16, 0, 0)

// ---------------- GEMM: C[M,N] = A[M,K](bf16) @ BT[N,K](bf16)^T ----------------
template <int EPI>
__global__ __launch_bounds__(256, 2) void gemm_bt(
    const u16* __restrict__ A, const u16* __restrict__ BT, int M, int N, int K,
    const float* __restrict__ bias, const float* __restrict__ resid,
    u16* __restrict__ outB, float* __restrict__ outF) {
  __shared__ __align__(16) u16 lA[128 * 32];
  __shared__ __align__(16) u16 lB[128 * 32];
  const int tid = threadIdx.x;
  const int wave = __builtin_amdgcn_readfirstlane(tid >> 6);
  const int lane = tid & 63;
  const int l15 = lane & 15, l4 = lane >> 4;
  const int wr = wave >> 1, wc = wave & 1;
  const int row0 = blockIdx.y * 128, col0 = blockIdx.x * 128;

  f32x4 acc[4][4] = {};

  for (int k0 = 0; k0 < K; k0 += 32) {
#pragma unroll
    for (int c = 0; c < 2; ++c) {
      const int idx = (c * 4 + wave) * 64 + lane;  // 16B-unit index 0..511
      const int r = idx >> 2, cb = (idx & 3) * 8;
      GLDS16(A + (size_t)(row0 + r) * K + k0 + cb, lA + (size_t)(c * 4 + wave) * 512);
      GLDS16(BT + (size_t)(col0 + r) * K + k0 + cb, lB + (size_t)(c * 4 + wave) * 512);
    }
    __syncthreads();
    s16x8 af[4], bfr[4];
#pragma unroll
    for (int m = 0; m < 4; ++m)
      af[m] = *(const s16x8*)&lA[(wr * 64 + m * 16 + l15) * 32 + l4 * 8];
#pragma unroll
    for (int n = 0; n < 4; ++n)
      bfr[n] = *(const s16x8*)&lB[(wc * 64 + n * 16 + l15) * 32 + l4 * 8];
#pragma unroll
    for (int m = 0; m < 4; ++m)
#pragma unroll
      for (int n = 0; n < 4; ++n)
        acc[m][n] = __builtin_amdgcn_mfma_f32_16x16x32_bf16(af[m], bfr[n], acc[m][n], 0, 0, 0);
    __syncthreads();
  }

#pragma unroll
  for (int m = 0; m < 4; ++m) {
    const int rowb = row0 + wr * 64 + m * 16 + l4 * 4;
#pragma unroll
    for (int n = 0; n < 4; ++n) {
      const int col = col0 + wc * 64 + n * 16 + l15;
#pragma unroll
      for (int j = 0; j < 4; ++j) {
        const int r = rowb + j;
        float v = acc[m][n][j];
        if (EPI == 0) {
          outB[(size_t)r * N + col] = f2bf(v);
        } else if (EPI == 1) {
          v += bias[col];
          outB[(size_t)r * N + col] = f2bf(v > 0.0f ? v : 0.0f);
        } else {
          v += bias[col] + resid[(size_t)r * N + col];
          outF[(size_t)r * N + col] = v;
        }
      }
    }
  }
}

// ---------------- weight transpose f32 -> bf16 ----------------
__global__ __launch_bounds__(256) void transpose_f32_bf16(
    const float* __restrict__ in, u16* __restrict__ out, int R, int C) {
  __shared__ float t[32][33];
  const int c0 = blockIdx.x * 32, r0 = blockIdx.y * 32;
  const int tx = threadIdx.x & 31, ty = threadIdx.x >> 5;
#pragma unroll
  for (int i = 0; i < 4; ++i)
    t[ty + i * 8][tx] = in[(size_t)(r0 + ty + i * 8) * C + c0 + tx];
  __syncthreads();
#pragma unroll
  for (int i = 0; i < 4; ++i)
    out[(size_t)(c0 + ty + i * 8) * R + r0 + tx] = f2bf(t[tx][ty + i * 8]);
}

// ---------------- batched bf16 transpose ----------------
__global__ __launch_bounds__(256) void transpose_bf16_b(
    const u16* __restrict__ in, u16* __restrict__ out, int R, int C) {
  __shared__ u16 t[32][34];
  const int b = blockIdx.z;
  const u16* pi = in + (size_t)b * R * C;
  u16* po = out + (size_t)b * R * C;
  const int c0 = blockIdx.x * 32, r0 = blockIdx.y * 32;
  const int tx = threadIdx.x & 31, ty = threadIdx.x >> 5;
#pragma unroll
  for (int i = 0; i < 4; ++i)
    t[ty + i * 8][tx] = pi[(size_t)(r0 + ty + i * 8) * C + c0 + tx];
  __syncthreads();
#pragma unroll
  for (int i = 0; i < 4; ++i)
    po[(size_t)(c0 + ty + i * 8) * R + r0 + tx] = t[tx][ty + i * 8];
}

// ---------------- f32 -> bf16 elementwise ----------------
__global__ __launch_bounds__(256) void cvt_f32_bf16(
    const float* __restrict__ in, u16* __restrict__ out, int n4) {
  const int i = blockIdx.x * 256 + threadIdx.x;
  if (i >= n4) return;
  f32x4 v = *(const f32x4*)&in[(size_t)i * 4];
  s16x4 o;
#pragma unroll
  for (int j = 0; j < 4; ++j) o[j] = (short)f2bf(v[j]);
  *(s16x4*)&out[(size_t)i * 4] = o;
}

// ---------------- LayerNorm over D=1024 ----------------
template <int WB>
__global__ __launch_bounds__(256) void layernorm_k(
    const float* __restrict__ in, const float* __restrict__ gm, const float* __restrict__ bt,
    float* __restrict__ outF, u16* __restrict__ outB) {
  const int row = blockIdx.x;
  const int t = threadIdx.x;
  const float* xr = in + (size_t)row * 1024;
  f32x4 v = *(const f32x4*)&xr[t * 4];
  float s = v[0] + v[1] + v[2] + v[3];
  float s2 = v[0] * v[0] + v[1] * v[1] + v[2] * v[2] + v[3] * v[3];
#pragma unroll
  for (int o = 32; o; o >>= 1) {
    s += __shfl_down(s, o);
    s2 += __shfl_down(s2, o);
  }
  __shared__ float red[8];
  const int lane = t & 63, wv = t >> 6;
  if (lane == 0) { red[wv] = s; red[4 + wv] = s2; }
  __syncthreads();
  s = red[0] + red[1] + red[2] + red[3];
  s2 = red[4] + red[5] + red[6] + red[7];
  const float mu = s * (1.0f / 1024.0f);
  const float var = fmaxf(s2 * (1.0f / 1024.0f) - mu * mu, 0.0f);
  const float rs = rsqrtf(var + 1e-5f);
  f32x4 g4 = *(const f32x4*)&gm[t * 4];
  f32x4 b4 = *(const f32x4*)&bt[t * 4];
  f32x4 ov;
#pragma unroll
  for (int j = 0; j < 4; ++j) ov[j] = (v[j] - mu) * rs * g4[j] + b4[j];
  *(f32x4*)&outF[(size_t)row * 1024 + t * 4] = ov;
  if (WB) {
    s16x4 ob;
#pragma unroll
    for (int j = 0; j < 4; ++j) ob[j] = (short)f2bf(ov[j]);
    *(s16x4*)&outB[(size_t)row * 1024 + t * 4] = ob;
  }
}

// ---------------- mask tile summary: any() over 64x64 tiles ----------------
__global__ __launch_bounds__(256) void mask_summary(
    const u8* __restrict__ mask, u8* __restrict__ msum) {
  const int kt = blockIdx.x, qt = blockIdx.y, b = blockIdx.z;
  const int tid = threadIdx.x;
  __shared__ int any_flag;
  if (tid == 0) any_flag = 0;
  __syncthreads();
  const u8* base = mask + ((size_t)(b * 2048 + qt * 64 + (tid >> 2))) * 2048 + kt * 64 + (tid & 3) * 16;
  const u32x4 v = *(const u32x4*)base;
  if (v[0] | v[1] | v[2] | v[3]) any_flag = 1;
  __syncthreads();
  if (tid == 0) msum[((size_t)b * 32 + qt) * 32 + kt] = (u8)any_flag;
}

// ---------------- flash attention (swapped-operand, LDS-free) ----------------
// grid (S/64, B*H), 256 threads = 4 independent waves; wave owns 16 q rows.
// Swapped QK^T: sc = mfma(K,Q) -> lane (l4,l15) holds S[kv=t*16+l4*4+j][q=l15].
// Swapped PV:   o  = mfma(VT,P) -> lane holds O[dk=n*16+l4*4+j][q=l15].
// Softmax state (m,l) lives at q=l15: reduce = in-reg + 2 shfl_xor, no broadcasts.
__global__ __launch_bounds__(256) void attn_k(
    const u16* __restrict__ Q, const u16* __restrict__ Kb, const u16* __restrict__ VT,
    const u8* __restrict__ mask, const u8* __restrict__ msum, u16* __restrict__ out) {
  const int S = 2048, Dm = 1024;
  const int bh = blockIdx.y, b = bh >> 4, h = bh & 15;
  const int wave = threadIdx.x >> 6, lane = threadIdx.x & 63;
  const int l15 = lane & 15, l4 = lane >> 4;
  const int q0 = blockIdx.x * 64 + wave * 16;
  const float CE = 0.125f * 1.44269504f;  // 1/sqrt(64) * log2(e)

  const size_t qoff = (size_t)(b * S + q0 + l15) * Dm + h * 64;
  const s16x8 qa0 = *(const s16x8*)&Q[qoff + l4 * 8];
  const s16x8 qa1 = *(const s16x8*)&Q[qoff + 32 + l4 * 8];

  f32x4 o[4] = {};
  float mr = -1e30f, lr = 0.0f;
  const u8* mb = mask + (size_t)b * S * S;
  const u8* msb = msum + (size_t)(b * 32 + blockIdx.x) * 32;
  const u16* vbase = VT + (size_t)bh * 64 * S;

  for (int kv = 0; kv < S; kv += 64) {
    // ---- QK^T (swapped) over 4 kv-tiles of 16 ----
    f32x4 sc[4];
    __builtin_amdgcn_s_setprio(1);
#pragma unroll
    for (int t = 0; t < 4; ++t) {
      const size_t koff = (size_t)(b * S + kv + t * 16 + l15) * Dm + h * 64;
      const s16x8 kf0 = *(const s16x8*)&Kb[koff + l4 * 8];
      const s16x8 kf1 = *(const s16x8*)&Kb[koff + 32 + l4 * 8];
      f32x4 z = {};
      z = __builtin_amdgcn_mfma_f32_16x16x32_bf16(kf0, qa0, z, 0, 0, 0);
      z = __builtin_amdgcn_mfma_f32_16x16x32_bf16(kf1, qa1, z, 0, 0, 0);
      sc[t] = z;
    }
    __builtin_amdgcn_s_setprio(0);
    // ---- mask (rare slow path via tile summary) ----
    if (msb[kv >> 6]) {
#pragma unroll
      for (int t = 0; t < 4; ++t) {
        const uchar4 m4 = *(const uchar4*)&mb[(size_t)(q0 + l15) * S + kv + t * 16 + l4 * 4];
        if (m4.x) sc[t][0] = -INFINITY;
        if (m4.y) sc[t][1] = -INFINITY;
        if (m4.z) sc[t][2] = -INFINITY;
        if (m4.w) sc[t][3] = -INFINITY;
      }
    }
    // ---- online softmax: in-register row stats (q = l15) ----
    float pm = sc[0][0];
#pragma unroll
    for (int t = 0; t < 4; ++t)
#pragma unroll
      for (int j = 0; j < 4; ++j) pm = fmaxf(pm, sc[t][j]);
    pm = fmaxf(pm, __shfl_xor(pm, 16));
    pm = fmaxf(pm, __shfl_xor(pm, 32));
    const float mn = fmaxf(mr, pm);
    const float al = exp2f((mr - mn) * CE);
    mr = mn;
    float rsum = 0.0f;
#pragma unroll
    for (int t = 0; t < 4; ++t)
#pragma unroll
      for (int j = 0; j < 4; ++j) {
        const float p = exp2f((sc[t][j] - mn) * CE);
        sc[t][j] = p;
        rsum += p;
      }
    rsum += __shfl_xor(rsum, 16);
    rsum += __shfl_xor(rsum, 32);
    lr = lr * al + rsum;
    // ---- rescale O (accumulator shares q=l15 mapping: no broadcast) ----
#pragma unroll
    for (int n = 0; n < 4; ++n)
#pragma unroll
      for (int j = 0; j < 4; ++j) o[n][j] *= al;
    // ---- pack P to bf16 dwords: dw[t][e] = (p[2e+1], p[2e]) ----
    u32 dw[4][2];
#pragma unroll
    for (int t = 0; t < 4; ++t)
#pragma unroll
      for (int e = 0; e < 2; ++e)
        dw[t][e] = (u32)f2bf(sc[t][2 * e]) | ((u32)f2bf(sc[t][2 * e + 1]) << 16);
    // ---- PV (swapped): per 32-kv step, exchange P into B-frag form ----
#pragma unroll
    for (int s = 0; s < 2; ++s) {
      u32 pad[4];
#pragma unroll
      for (int d = 0; d < 4; ++d) {
        const int src = (((l4 & 1) * 2 + (d >> 1)) << 4) + l15;
        const u32 v0 = (u32)__shfl((int)dw[2 * s][d & 1], src);
        const u32 v1 = (u32)__shfl((int)dw[2 * s + 1][d & 1], src);
        pad[d] = (l4 >> 1) ? v1 : v0;
      }
      const s16x8 pa = __builtin_bit_cast(s16x8, u32x4{pad[0], pad[1], pad[2], pad[3]});
      __builtin_amdgcn_s_setprio(1);
#pragma unroll
      for (int n = 0; n < 4; ++n) {
        const s16x8 vb = *(const s16x8*)&vbase[(size_t)(n * 16 + l15) * S + kv + s * 32 + l4 * 8];
        o[n] = __builtin_amdgcn_mfma_f32_16x16x32_bf16(vb, pa, o[n], 0, 0, 0);
      }
      __builtin_amdgcn_s_setprio(0);
    }
  }
  // ---- epilogue: normalize (l at q=l15 matches o mapping), pack, store ----
  const float inv = lr > 0.0f ? 1.0f / lr : 0.0f;
  const size_t obase = (size_t)(b * S + q0 + l15) * Dm + h * 64;
#pragma unroll
  for (int n = 0; n < 4; ++n) {
    s16x4 ov;
#pragma unroll
    for (int j = 0; j < 4; ++j) ov[j] = (short)f2bf(o[n][j] * inv);
    *(s16x4*)&out[obase + n * 16 + l4 * 4] = ov;
  }
}

extern "C" void kernel_launch(void* const* d_in, const int* in_sizes, int n_in,
                              void* d_out, int out_size, void* d_ws, size_t ws_size,
                              hipStream_t stream) {
  (void)in_sizes; (void)n_in; (void)out_size; (void)ws_size;
  const float* x = (const float*)d_in[0];
  const u8* mask = (const u8*)d_in[1];
  const float* Wq = (const float*)d_in[2];
  const float* Wk = (const float*)d_in[3];
  const float* Wv = (const float*)d_in[4];
  const float* Wo = (const float*)d_in[5];
  const float* bo = (const float*)d_in[6];
  const float* W1 = (const float*)d_in[7];
  const float* b1 = (const float*)d_in[8];
  const float* W2 = (const float*)d_in[9];
  const float* b2 = (const float*)d_in[10];
  const float* g1 = (const float*)d_in[11];
  const float* be1 = (const float*)d_in[12];
  const float* g2 = (const float*)d_in[13];
  const float* be2 = (const float*)d_in[14];
  float* outp = (float*)d_out;

  const int B = 2, S = 2048, D = 1024, FF = 4096;
  const int M = B * S;  // 4096
  char* w = (char*)d_ws;
  const size_t MB = 1024 * 1024;
  u16* wqT = (u16*)(w + 0 * MB);
  u16* wkT = (u16*)(w + 2 * MB);
  u16* wvT = (u16*)(w + 4 * MB);
  u16* woT = (u16*)(w + 6 * MB);
  u16* w1T = (u16*)(w + 8 * MB);
  u16* w2T = (u16*)(w + 16 * MB);
  u16* xb  = (u16*)(w + 24 * MB);
  u16* qb  = (u16*)(w + 32 * MB);
  u16* kb  = (u16*)(w + 40 * MB);
  u16* vb  = (u16*)(w + 48 * MB);
  u16* vt  = (u16*)(w + 56 * MB);
  float* x0f = (float*)(w + 64 * MB);   // written AFTER attention (stream-ordered)
  float* x1f = (float*)(w + 80 * MB);
  u16* x1b = (u16*)(w + 96 * MB);
  u8* msum = (u8*)(w + 64 * MB);        // 2 KB, lives only until attn_k completes
  u16* attn_o = vb;
  u16* ff1 = (u16*)(w + 24 * MB);
  float* y0f = x0f;

  // weight prep
  transpose_f32_bf16<<<dim3(32, 32), 256, 0, stream>>>(Wq, wqT, 1024, 1024);
  transpose_f32_bf16<<<dim3(32, 32), 256, 0, stream>>>(Wk, wkT, 1024, 1024);
  transpose_f32_bf16<<<dim3(32, 32), 256, 0, stream>>>(Wv, wvT, 1024, 1024);
  transpose_f32_bf16<<<dim3(32, 32), 256, 0, stream>>>(Wo, woT, 1024, 1024);
  transpose_f32_bf16<<<dim3(128, 32), 256, 0, stream>>>(W1, w1T, 1024, 4096);
  transpose_f32_bf16<<<dim3(32, 128), 256, 0, stream>>>(W2, w2T, 4096, 1024);
  cvt_f32_bf16<<<dim3(M * D / 4 / 256), 256, 0, stream>>>(x, xb, M * D / 4);
  mask_summary<<<dim3(32, 32, 2), 256, 0, stream>>>(mask, msum);

  // QKV projections
  gemm_bt<0><<<dim3(D / 128, M / 128), 256, 0, stream>>>(xb, wqT, M, D, D, nullptr, nullptr, qb, nullptr);
  gemm_bt<0><<<dim3(D / 128, M / 128), 256, 0, stream>>>(xb, wkT, M, D, D, nullptr, nullptr, kb, nullptr);
  gemm_bt<0><<<dim3(D / 128, M / 128), 256, 0, stream>>>(xb, wvT, M, D, D, nullptr, nullptr, vb, nullptr);
  transpose_bf16_b<<<dim3(32, 64, 2), 256, 0, stream>>>(vb, vt, 2048, 1024);

  // attention
  attn_k<<<dim3(S / 64, 32), 256, 0, stream>>>(qb, kb, vt, mask, msum, attn_o);

  // Wo projection + bias + residual(x)
  gemm_bt<2><<<dim3(D / 128, M / 128), 256, 0, stream>>>(attn_o, woT, M, D, D, bo, x, nullptr, x0f);
  layernorm_k<1><<<dim3(M), 256, 0, stream>>>(x0f, g1, be1, x1f, x1b);
  gemm_bt<1><<<dim3(FF / 128, M / 128), 256, 0, stream>>>(x1b, w1T, M, FF, D, b1, nullptr, ff1, nullptr);
  gemm_bt<2><<<dim3(D / 128, M / 128), 256, 0, stream>>>(ff1, w2T, M, D, FF, b2, x1f, nullptr, y0f);
  layernorm_k<0><<<dim3(M), 256, 0, stream>>>(y0f, g2, be2, outp, nullptr);
}

// Round 3
// 359.559 us; speedup vs baseline: 1.4037x; 1.3747x over previous
//
#include <hip/hip_runtime.h>
#include <math.h>

typedef unsigned short u16;
typedef unsigned char u8;
typedef unsigned int u32;
typedef __attribute__((ext_vector_type(4))) float f32x4;
typedef __attribute__((ext_vector_type(8))) short s16x8;
typedef __attribute__((ext_vector_type(4))) short s16x4;
typedef __attribute__((ext_vector_type(4))) u32 u32x4;

__device__ __forceinline__ u16 f2bf(float f) {
  unsigned u = __builtin_bit_cast(unsigned, f);
  u += 0x7fffu + ((u >> 16) & 1u);
  return (u16)(u >> 16);
}

#define GLDS16(g, l) __builtin_amdgcn_global_load_lds( \
    (const __attribute__((address_space(1))) void*)(g), \
    (__attribute__((address_space(3))) void*)(l), 16, 0, 0)

// ---------------- GEMM: C[M,N] = A[M,K](bf16) @ BT[N,K](bf16)^T ----------------
template <int EPI>
__global__ __launch_bounds__(256, 2) void gemm_bt(
    const u16* __restrict__ A, const u16* __restrict__ BT, int M, int N, int K,
    const float* __restrict__ bias, const float* __restrict__ resid,
    u16* __restrict__ outB, float* __restrict__ outF) {
  __shared__ __align__(16) u16 lA[128 * 32];
  __shared__ __align__(16) u16 lB[128 * 32];
  const int tid = threadIdx.x;
  const int wave = __builtin_amdgcn_readfirstlane(tid >> 6);
  const int lane = tid & 63;
  const int l15 = lane & 15, l4 = lane >> 4;
  const int wr = wave >> 1, wc = wave & 1;
  const int row0 = blockIdx.y * 128, col0 = blockIdx.x * 128;

  f32x4 acc[4][4] = {};

  for (int k0 = 0; k0 < K; k0 += 32) {
#pragma unroll
    for (int c = 0; c < 2; ++c) {
      const int idx = (c * 4 + wave) * 64 + lane;  // 16B-unit index 0..511
      const int r = idx >> 2, cb = (idx & 3) * 8;
      GLDS16(A + (size_t)(row0 + r) * K + k0 + cb, lA + (size_t)(c * 4 + wave) * 512);
      GLDS16(BT + (size_t)(col0 + r) * K + k0 + cb, lB + (size_t)(c * 4 + wave) * 512);
    }
    __syncthreads();
    s16x8 af[4], bfr[4];
#pragma unroll
    for (int m = 0; m < 4; ++m)
      af[m] = *(const s16x8*)&lA[(wr * 64 + m * 16 + l15) * 32 + l4 * 8];
#pragma unroll
    for (int n = 0; n < 4; ++n)
      bfr[n] = *(const s16x8*)&lB[(wc * 64 + n * 16 + l15) * 32 + l4 * 8];
#pragma unroll
    for (int m = 0; m < 4; ++m)
#pragma unroll
      for (int n = 0; n < 4; ++n)
        acc[m][n] = __builtin_amdgcn_mfma_f32_16x16x32_bf16(af[m], bfr[n], acc[m][n], 0, 0, 0);
    __syncthreads();
  }

#pragma unroll
  for (int m = 0; m < 4; ++m) {
    const int rowb = row0 + wr * 64 + m * 16 + l4 * 4;
#pragma unroll
    for (int n = 0; n < 4; ++n) {
      const int col = col0 + wc * 64 + n * 16 + l15;
#pragma unroll
      for (int j = 0; j < 4; ++j) {
        const int r = rowb + j;
        float v = acc[m][n][j];
        if (EPI == 0) {
          outB[(size_t)r * N + col] = f2bf(v);
        } else if (EPI == 1) {
          v += bias[col];
          outB[(size_t)r * N + col] = f2bf(v > 0.0f ? v : 0.0f);
        } else {
          v += bias[col] + resid[(size_t)r * N + col];
          outF[(size_t)r * N + col] = v;
        }
      }
    }
  }
}

// ---------------- weight transpose f32 -> bf16 ----------------
__global__ __launch_bounds__(256) void transpose_f32_bf16(
    const float* __restrict__ in, u16* __restrict__ out, int R, int C) {
  __shared__ float t[32][33];
  const int c0 = blockIdx.x * 32, r0 = blockIdx.y * 32;
  const int tx = threadIdx.x & 31, ty = threadIdx.x >> 5;
#pragma unroll
  for (int i = 0; i < 4; ++i)
    t[ty + i * 8][tx] = in[(size_t)(r0 + ty + i * 8) * C + c0 + tx];
  __syncthreads();
#pragma unroll
  for (int i = 0; i < 4; ++i)
    out[(size_t)(c0 + ty + i * 8) * R + r0 + tx] = f2bf(t[tx][ty + i * 8]);
}

// ---------------- batched bf16 transpose ----------------
__global__ __launch_bounds__(256) void transpose_bf16_b(
    const u16* __restrict__ in, u16* __restrict__ out, int R, int C) {
  __shared__ u16 t[32][34];
  const int b = blockIdx.z;
  const u16* pi = in + (size_t)b * R * C;
  u16* po = out + (size_t)b * R * C;
  const int c0 = blockIdx.x * 32, r0 = blockIdx.y * 32;
  const int tx = threadIdx.x & 31, ty = threadIdx.x >> 5;
#pragma unroll
  for (int i = 0; i < 4; ++i)
    t[ty + i * 8][tx] = pi[(size_t)(r0 + ty + i * 8) * C + c0 + tx];
  __syncthreads();
#pragma unroll
  for (int i = 0; i < 4; ++i)
    po[(size_t)(c0 + ty + i * 8) * R + r0 + tx] = t[tx][ty + i * 8];
}

// ---------------- f32 -> bf16 elementwise ----------------
__global__ __launch_bounds__(256) void cvt_f32_bf16(
    const float* __restrict__ in, u16* __restrict__ out, int n4) {
  const int i = blockIdx.x * 256 + threadIdx.x;
  if (i >= n4) return;
  f32x4 v = *(const f32x4*)&in[(size_t)i * 4];
  s16x4 o;
#pragma unroll
  for (int j = 0; j < 4; ++j) o[j] = (short)f2bf(v[j]);
  *(s16x4*)&out[(size_t)i * 4] = o;
}

// ---------------- LayerNorm over D=1024 ----------------
template <int WB>
__global__ __launch_bounds__(256) void layernorm_k(
    const float* __restrict__ in, const float* __restrict__ gm, const float* __restrict__ bt,
    float* __restrict__ outF, u16* __restrict__ outB) {
  const int row = blockIdx.x;
  const int t = threadIdx.x;
  const float* xr = in + (size_t)row * 1024;
  f32x4 v = *(const f32x4*)&xr[t * 4];
  float s = v[0] + v[1] + v[2] + v[3];
  float s2 = v[0] * v[0] + v[1] * v[1] + v[2] * v[2] + v[3] * v[3];
#pragma unroll
  for (int o = 32; o; o >>= 1) {
    s += __shfl_down(s, o);
    s2 += __shfl_down(s2, o);
  }
  __shared__ float red[8];
  const int lane = t & 63, wv = t >> 6;
  if (lane == 0) { red[wv] = s; red[4 + wv] = s2; }
  __syncthreads();
  s = red[0] + red[1] + red[2] + red[3];
  s2 = red[4] + red[5] + red[6] + red[7];
  const float mu = s * (1.0f / 1024.0f);
  const float var = fmaxf(s2 * (1.0f / 1024.0f) - mu * mu, 0.0f);
  const float rs = rsqrtf(var + 1e-5f);
  f32x4 g4 = *(const f32x4*)&gm[t * 4];
  f32x4 b4 = *(const f32x4*)&bt[t * 4];
  f32x4 ov;
#pragma unroll
  for (int j = 0; j < 4; ++j) ov[j] = (v[j] - mu) * rs * g4[j] + b4[j];
  *(f32x4*)&outF[(size_t)row * 1024 + t * 4] = ov;
  if (WB) {
    s16x4 ob;
#pragma unroll
    for (int j = 0; j < 4; ++j) ob[j] = (short)f2bf(ov[j]);
    *(s16x4*)&outB[(size_t)row * 1024 + t * 4] = ob;
  }
}

// ---------------- mask tile summary: any() over 64x64 tiles ----------------
__global__ __launch_bounds__(256) void mask_summary(
    const u8* __restrict__ mask, u8* __restrict__ msum) {
  const int kt = blockIdx.x, qt = blockIdx.y, b = blockIdx.z;
  const int tid = threadIdx.x;
  __shared__ int any_flag;
  if (tid == 0) any_flag = 0;
  __syncthreads();
  const u8* base = mask + ((size_t)(b * 2048 + qt * 64 + (tid >> 2))) * 2048 + kt * 64 + (tid & 3) * 16;
  const u32x4 v = *(const u32x4*)base;
  if (v[0] | v[1] | v[2] | v[3]) any_flag = 1;
  __syncthreads();
  if (tid == 0) msum[((size_t)b * 32 + qt) * 32 + kt] = (u8)any_flag;
}

// ---------------- flash attention (LDS-staged K/V, XCD-swizzled, dbuf) ----------------
// grid 1024 blocks; in-kernel remap: xcd=wgid&7 owns bh in [xcd*4, xcd*4+4) so each
// (b,h)'s K/VT slice (512 KB) stays L2-resident on one XCD (4x512KB=2MB < 4MB L2).
// 4 waves/block; wave owns 16 q rows. K and VT tiles (64x64 bf16, XOR-swizzled rows)
// double-buffered in LDS: stage(next) issued before compute(cur), 1 barrier/iter.
__global__ __launch_bounds__(256) void attn_k(
    const u16* __restrict__ Q, const u16* __restrict__ Kb, const u16* __restrict__ VT,
    const u8* __restrict__ mask, const u8* __restrict__ msum, u16* __restrict__ out) {
  const int S = 2048, Dm = 1024;
  const int wgid = blockIdx.x + gridDim.x * blockIdx.y;  // 0..1023
  const int xcd = wgid & 7, slot = wgid >> 3;
  const int bh = xcd * 4 + (slot >> 5);
  const int qt = slot & 31;
  const int b = bh >> 4, h = bh & 15;
  const int wave = threadIdx.x >> 6, lane = threadIdx.x & 63;
  const int l15 = lane & 15, l4 = lane >> 4;
  const int q0 = qt * 64 + wave * 16;
  const float CE = 0.125f * 1.44269504f;  // 1/sqrt(64) * log2(e)

  __shared__ __align__(16) u16 lK[2][4096];  // [buf][64 rows x 64 cols], XOR-swizzled
  __shared__ __align__(16) u16 lV[2][4096];

  const size_t qoff = (size_t)(b * S + q0 + l15) * Dm + h * 64;
  const s16x8 qa0 = *(const s16x8*)&Q[qoff + l4 * 8];
  const s16x8 qa1 = *(const s16x8*)&Q[qoff + 32 + l4 * 8];

  f32x4 o[4] = {};
  float mr = -1e30f, lr = 0.0f;
  const u8* mb = mask + (size_t)b * S * S;
  const u8* msb = msum + (size_t)(b * 32 + qt) * 32;
  const u16* vbase = VT + (size_t)bh * 64 * S;
  const int bS = b * S;

  // stage K/VT 64x64 tiles at kv into buffer bi; LDS dest linear, global source
  // pre-swizzled: LDS[row][cb] = G[row][cb ^ ((row&7)<<4)] (byte addressing).
  auto stage = [&](int bi, int kvv) {
#pragma unroll
    for (int c = 0; c < 2; ++c) {
      const int byt = ((c * 4 + wave) * 64 + lane) * 16;  // 0..8191
      const int row = byt >> 7;
      const int cb = (byt & 127) ^ ((row & 7) << 4);
      GLDS16(Kb + (size_t)(bS + kvv + row) * Dm + h * 64 + (cb >> 1),
             &lK[bi][(c * 4 + wave) * 512]);
      GLDS16(vbase + (size_t)row * S + kvv + (cb >> 1),
             &lV[bi][(c * 4 + wave) * 512]);
    }
  };

  stage(0, 0);
  __syncthreads();  // drains vmcnt(0) before barrier (compiler-emitted)
  int buf = 0;

  for (int kv = 0; kv < S; kv += 64) {
    if (kv + 64 < S) stage(buf ^ 1, kv + 64);  // async prefetch; drained at loop-end barrier
    const char* kbuf = (const char*)&lK[buf][0];
    const char* vbuf = (const char*)&lV[buf][0];

    // ---- QK^T (swapped): sc = mfma(K,Q); lane holds S^T[kv=t*16+l4*4+j][q=l15] ----
    f32x4 sc[4];
    __builtin_amdgcn_s_setprio(1);
#pragma unroll
    for (int t = 0; t < 4; ++t) {
      const int row = t * 16 + l15;
      const int sw = (row & 7) << 4;
      const s16x8 kf0 = *(const s16x8*)(kbuf + row * 128 + ((l4 * 16) ^ sw));
      const s16x8 kf1 = *(const s16x8*)(kbuf + row * 128 + ((64 + l4 * 16) ^ sw));
      f32x4 z = {};
      z = __builtin_amdgcn_mfma_f32_16x16x32_bf16(kf0, qa0, z, 0, 0, 0);
      z = __builtin_amdgcn_mfma_f32_16x16x32_bf16(kf1, qa1, z, 0, 0, 0);
      sc[t] = z;
    }
    __builtin_amdgcn_s_setprio(0);
    // ---- mask (rare slow path via tile summary) ----
    if (msb[kv >> 6]) {
#pragma unroll
      for (int t = 0; t < 4; ++t) {
        const uchar4 m4 = *(const uchar4*)&mb[(size_t)(q0 + l15) * S + kv + t * 16 + l4 * 4];
        if (m4.x) sc[t][0] = -INFINITY;
        if (m4.y) sc[t][1] = -INFINITY;
        if (m4.z) sc[t][2] = -INFINITY;
        if (m4.w) sc[t][3] = -INFINITY;
      }
    }
    // ---- online softmax (q = l15 in-register stats, 2 shuffles total) ----
    float pm = sc[0][0];
#pragma unroll
    for (int t = 0; t < 4; ++t)
#pragma unroll
      for (int j = 0; j < 4; ++j) pm = fmaxf(pm, sc[t][j]);
    pm = fmaxf(pm, __shfl_xor(pm, 16));
    pm = fmaxf(pm, __shfl_xor(pm, 32));
    const float mn = fmaxf(mr, pm);
    const float al = exp2f((mr - mn) * CE);
    mr = mn;
    float rsum = 0.0f;
#pragma unroll
    for (int t = 0; t < 4; ++t)
#pragma unroll
      for (int j = 0; j < 4; ++j) {
        const float p = exp2f((sc[t][j] - mn) * CE);
        sc[t][j] = p;
        rsum += p;
      }
    rsum += __shfl_xor(rsum, 16);
    rsum += __shfl_xor(rsum, 32);
    lr = lr * al + rsum;
#pragma unroll
    for (int n = 0; n < 4; ++n)
#pragma unroll
      for (int j = 0; j < 4; ++j) o[n][j] *= al;
    // ---- pack P to bf16 dwords ----
    u32 dw[4][2];
#pragma unroll
    for (int t = 0; t < 4; ++t)
#pragma unroll
      for (int e = 0; e < 2; ++e)
        dw[t][e] = (u32)f2bf(sc[t][2 * e]) | ((u32)f2bf(sc[t][2 * e + 1]) << 16);
    // ---- PV (swapped): exchange P into B-frag form, V from LDS ----
#pragma unroll
    for (int s = 0; s < 2; ++s) {
      u32 pad[4];
#pragma unroll
      for (int d = 0; d < 4; ++d) {
        const int src = (((l4 & 1) * 2 + (d >> 1)) << 4) + l15;
        const u32 v0 = (u32)__shfl((int)dw[2 * s][d & 1], src);
        const u32 v1 = (u32)__shfl((int)dw[2 * s + 1][d & 1], src);
        pad[d] = (l4 >> 1) ? v1 : v0;
      }
      const s16x8 pa = __builtin_bit_cast(s16x8, u32x4{pad[0], pad[1], pad[2], pad[3]});
      __builtin_amdgcn_s_setprio(1);
#pragma unroll
      for (int n = 0; n < 4; ++n) {
        const int row = n * 16 + l15;
        const int sw = (row & 7) << 4;
        const s16x8 vb = *(const s16x8*)(vbuf + row * 128 + ((s * 64 + l4 * 16) ^ sw));
        o[n] = __builtin_amdgcn_mfma_f32_16x16x32_bf16(vb, pa, o[n], 0, 0, 0);
      }
      __builtin_amdgcn_s_setprio(0);
    }
    __syncthreads();  // drains prefetch vmcnt + protects buf swap
    buf ^= 1;
  }
  // ---- epilogue ----
  const float inv = lr > 0.0f ? 1.0f / lr : 0.0f;
  const size_t obase = (size_t)(b * S + q0 + l15) * Dm + h * 64;
#pragma unroll
  for (int n = 0; n < 4; ++n) {
    s16x4 ov;
#pragma unroll
    for (int j = 0; j < 4; ++j) ov[j] = (short)f2bf(o[n][j] * inv);
    *(s16x4*)&out[obase + n * 16 + l4 * 4] = ov;
  }
}

extern "C" void kernel_launch(void* const* d_in, const int* in_sizes, int n_in,
                              void* d_out, int out_size, void* d_ws, size_t ws_size,
                              hipStream_t stream) {
  (void)in_sizes; (void)n_in; (void)out_size; (void)ws_size;
  const float* x = (const float*)d_in[0];
  const u8* mask = (const u8*)d_in[1];
  const float* Wq = (const float*)d_in[2];
  const float* Wk = (const float*)d_in[3];
  const float* Wv = (const float*)d_in[4];
  const float* Wo = (const float*)d_in[5];
  const float* bo = (const float*)d_in[6];
  const float* W1 = (const float*)d_in[7];
  const float* b1 = (const float*)d_in[8];
  const float* W2 = (const float*)d_in[9];
  const float* b2 = (const float*)d_in[10];
  const float* g1 = (const float*)d_in[11];
  const float* be1 = (const float*)d_in[12];
  const float* g2 = (const float*)d_in[13];
  const float* be2 = (const float*)d_in[14];
  float* outp = (float*)d_out;

  const int B = 2, S = 2048, D = 1024, FF = 4096;
  const int M = B * S;  // 4096
  char* w = (char*)d_ws;
  const size_t MB = 1024 * 1024;
  u16* wqT = (u16*)(w + 0 * MB);
  u16* wkT = (u16*)(w + 2 * MB);
  u16* wvT = (u16*)(w + 4 * MB);
  u16* woT = (u16*)(w + 6 * MB);
  u16* w1T = (u16*)(w + 8 * MB);
  u16* w2T = (u16*)(w + 16 * MB);
  u16* xb  = (u16*)(w + 24 * MB);
  u16* qb  = (u16*)(w + 32 * MB);
  u16* kb  = (u16*)(w + 40 * MB);
  u16* vb  = (u16*)(w + 48 * MB);
  u16* vt  = (u16*)(w + 56 * MB);
  float* x0f = (float*)(w + 64 * MB);
  float* x1f = (float*)(w + 80 * MB);
  u16* x1b = (u16*)(w + 96 * MB);
  u8* msum = (u8*)(w + 64 * MB);  // 2 KB, dead before x0f is written
  u16* attn_o = vb;
  u16* ff1 = (u16*)(w + 24 * MB);
  float* y0f = x0f;

  // weight prep
  transpose_f32_bf16<<<dim3(32, 32), 256, 0, stream>>>(Wq, wqT, 1024, 1024);
  transpose_f32_bf16<<<dim3(32, 32), 256, 0, stream>>>(Wk, wkT, 1024, 1024);
  transpose_f32_bf16<<<dim3(32, 32), 256, 0, stream>>>(Wv, wvT, 1024, 1024);
  transpose_f32_bf16<<<dim3(32, 32), 256, 0, stream>>>(Wo, woT, 1024, 1024);
  transpose_f32_bf16<<<dim3(128, 32), 256, 0, stream>>>(W1, w1T, 1024, 4096);
  transpose_f32_bf16<<<dim3(32, 128), 256, 0, stream>>>(W2, w2T, 4096, 1024);
  cvt_f32_bf16<<<dim3(M * D / 4 / 256), 256, 0, stream>>>(x, xb, M * D / 4);
  mask_summary<<<dim3(32, 32, 2), 256, 0, stream>>>(mask, msum);

  // QKV projections
  gemm_bt<0><<<dim3(D / 128, M / 128), 256, 0, stream>>>(xb, wqT, M, D, D, nullptr, nullptr, qb, nullptr);
  gemm_bt<0><<<dim3(D / 128, M / 128), 256, 0, stream>>>(xb, wkT, M, D, D, nullptr, nullptr, kb, nullptr);
  gemm_bt<0><<<dim3(D / 128, M / 128), 256, 0, stream>>>(xb, wvT, M, D, D, nullptr, nullptr, vb, nullptr);
  transpose_bf16_b<<<dim3(32, 64, 2), 256, 0, stream>>>(vb, vt, 2048, 1024);

  // attention
  attn_k<<<dim3(32, 32), 256, 0, stream>>>(qb, kb, vt, mask, msum, attn_o);

  // Wo projection + bias + residual(x)
  gemm_bt<2><<<dim3(D / 128, M / 128), 256, 0, stream>>>(attn_o, woT, M, D, D, bo, x, nullptr, x0f);
  layernorm_k<1><<<dim3(M), 256, 0, stream>>>(x0f, g1, be1, x1f, x1b);
  gemm_bt<1><<<dim3(FF / 128, M / 128), 256, 0, stream>>>(x1b, w1T, M, FF, D, b1, nullptr, ff1, nullptr);
  gemm_bt<2><<<dim3(D / 128, M / 128), 256, 0, stream>>>(ff1, w2T, M, D, FF, b2, x1f, nullptr, y0f);
  layernorm_k<0><<<dim3(M), 256, 0, stream>>>(y0f, g2, be2, outp, nullptr);
}

// Round 4
// 321.520 us; speedup vs baseline: 1.5698x; 1.1183x over previous
//
#include <hip/hip_runtime.h>
#include <math.h>

typedef unsigned short u16;
typedef unsigned char u8;
typedef unsigned int u32;
typedef __attribute__((ext_vector_type(4))) float f32x4;
typedef __attribute__((ext_vector_type(8))) short s16x8;
typedef __attribute__((ext_vector_type(4))) short s16x4;
typedef __attribute__((ext_vector_type(4))) u32 u32x4;
typedef __attribute__((ext_vector_type(2))) u32 u32x2;

__device__ __forceinline__ u16 f2bf(float f) {
  unsigned u = __builtin_bit_cast(unsigned, f);
  u += 0x7fffu + ((u >> 16) & 1u);
  return (u16)(u >> 16);
}

#define GLDS16(g, l) __builtin_amdgcn_global_load_lds( \
    (const __attribute__((address_space(1))) void*)(g), \
    (__attribute__((address_space(3))) void*)(l), 16, 0, 0)

// ---------------- GEMM: C[M,N] = A[M,K](bf16) @ BT[N,K](bf16)^T ----------------
// 2-phase double-buffered staging: prefetch next K-tile during compute (T3-min).
template <int EPI>
__global__ __launch_bounds__(256, 2) void gemm_bt(
    const u16* __restrict__ A, const u16* __restrict__ BT, int M, int N, int K,
    const float* __restrict__ bias, const float* __restrict__ resid,
    u16* __restrict__ outB, float* __restrict__ outF) {
  __shared__ __align__(16) u16 lA[2][128 * 32];
  __shared__ __align__(16) u16 lB[2][128 * 32];
  const int tid = threadIdx.x;
  const int wave = __builtin_amdgcn_readfirstlane(tid >> 6);
  const int lane = tid & 63;
  const int l15 = lane & 15, l4 = lane >> 4;
  const int wr = wave >> 1, wc = wave & 1;
  const int row0 = blockIdx.y * 128, col0 = blockIdx.x * 128;

  f32x4 acc[4][4] = {};

  auto stage = [&](int bi, int k0) {
#pragma unroll
    for (int c = 0; c < 2; ++c) {
      const int idx = (c * 4 + wave) * 64 + lane;  // 16B-unit index 0..511
      const int r = idx >> 2, cb = (idx & 3) * 8;
      GLDS16(A + (size_t)(row0 + r) * K + k0 + cb, &lA[bi][(c * 4 + wave) * 512]);
      GLDS16(BT + (size_t)(col0 + r) * K + k0 + cb, &lB[bi][(c * 4 + wave) * 512]);
    }
  };

  stage(0, 0);
  __syncthreads();
  int buf = 0;

  for (int k0 = 0; k0 < K; k0 += 32) {
    if (k0 + 32 < K) stage(buf ^ 1, k0 + 32);  // async prefetch, drained at loop-end barrier
    s16x8 af[4], bfr[4];
#pragma unroll
    for (int m = 0; m < 4; ++m)
      af[m] = *(const s16x8*)&lA[buf][(wr * 64 + m * 16 + l15) * 32 + l4 * 8];
#pragma unroll
    for (int n = 0; n < 4; ++n)
      bfr[n] = *(const s16x8*)&lB[buf][(wc * 64 + n * 16 + l15) * 32 + l4 * 8];
#pragma unroll
    for (int m = 0; m < 4; ++m)
#pragma unroll
      for (int n = 0; n < 4; ++n)
        acc[m][n] = __builtin_amdgcn_mfma_f32_16x16x32_bf16(af[m], bfr[n], acc[m][n], 0, 0, 0);
    __syncthreads();
    buf ^= 1;
  }

#pragma unroll
  for (int m = 0; m < 4; ++m) {
    const int rowb = row0 + wr * 64 + m * 16 + l4 * 4;
#pragma unroll
    for (int n = 0; n < 4; ++n) {
      const int col = col0 + wc * 64 + n * 16 + l15;
#pragma unroll
      for (int j = 0; j < 4; ++j) {
        const int r = rowb + j;
        float v = acc[m][n][j];
        if (EPI == 0) {
          outB[(size_t)r * N + col] = f2bf(v);
        } else if (EPI == 1) {
          v += bias[col];
          outB[(size_t)r * N + col] = f2bf(v > 0.0f ? v : 0.0f);
        } else {
          v += bias[col] + resid[(size_t)r * N + col];
          outF[(size_t)r * N + col] = v;
        }
      }
    }
  }
}

// ---------------- weight transpose f32 -> bf16 ----------------
__global__ __launch_bounds__(256) void transpose_f32_bf16(
    const float* __restrict__ in, u16* __restrict__ out, int R, int C) {
  __shared__ float t[32][33];
  const int c0 = blockIdx.x * 32, r0 = blockIdx.y * 32;
  const int tx = threadIdx.x & 31, ty = threadIdx.x >> 5;
#pragma unroll
  for (int i = 0; i < 4; ++i)
    t[ty + i * 8][tx] = in[(size_t)(r0 + ty + i * 8) * C + c0 + tx];
  __syncthreads();
#pragma unroll
  for (int i = 0; i < 4; ++i)
    out[(size_t)(c0 + ty + i * 8) * R + r0 + tx] = f2bf(t[tx][ty + i * 8]);
}

// ---------------- batched bf16 transpose (strided input, col-offset) ----------------
// out[b][c][r] = in[b*R*rstr + r*rstr + coff + c]
__global__ __launch_bounds__(256) void transpose_bf16_b(
    const u16* __restrict__ in, u16* __restrict__ out, int R, int C, int rstr, int coff) {
  __shared__ u16 t[32][34];
  const int b = blockIdx.z;
  const u16* pi = in + (size_t)b * R * rstr + coff;
  u16* po = out + (size_t)b * R * C;
  const int c0 = blockIdx.x * 32, r0 = blockIdx.y * 32;
  const int tx = threadIdx.x & 31, ty = threadIdx.x >> 5;
#pragma unroll
  for (int i = 0; i < 4; ++i)
    t[ty + i * 8][tx] = pi[(size_t)(r0 + ty + i * 8) * rstr + c0 + tx];
  __syncthreads();
#pragma unroll
  for (int i = 0; i < 4; ++i)
    po[(size_t)(c0 + ty + i * 8) * R + r0 + tx] = t[tx][ty + i * 8];
}

// ---------------- f32 -> bf16 elementwise ----------------
__global__ __launch_bounds__(256) void cvt_f32_bf16(
    const float* __restrict__ in, u16* __restrict__ out, int n4) {
  const int i = blockIdx.x * 256 + threadIdx.x;
  if (i >= n4) return;
  f32x4 v = *(const f32x4*)&in[(size_t)i * 4];
  s16x4 o;
#pragma unroll
  for (int j = 0; j < 4; ++j) o[j] = (short)f2bf(v[j]);
  *(s16x4*)&out[(size_t)i * 4] = o;
}

// ---------------- LayerNorm over D=1024 ----------------
template <int WB>
__global__ __launch_bounds__(256) void layernorm_k(
    const float* __restrict__ in, const float* __restrict__ gm, const float* __restrict__ bt,
    float* __restrict__ outF, u16* __restrict__ outB) {
  const int row = blockIdx.x;
  const int t = threadIdx.x;
  const float* xr = in + (size_t)row * 1024;
  f32x4 v = *(const f32x4*)&xr[t * 4];
  float s = v[0] + v[1] + v[2] + v[3];
  float s2 = v[0] * v[0] + v[1] * v[1] + v[2] * v[2] + v[3] * v[3];
#pragma unroll
  for (int o = 32; o; o >>= 1) {
    s += __shfl_down(s, o);
    s2 += __shfl_down(s2, o);
  }
  __shared__ float red[8];
  const int lane = t & 63, wv = t >> 6;
  if (lane == 0) { red[wv] = s; red[4 + wv] = s2; }
  __syncthreads();
  s = red[0] + red[1] + red[2] + red[3];
  s2 = red[4] + red[5] + red[6] + red[7];
  const float mu = s * (1.0f / 1024.0f);
  const float var = fmaxf(s2 * (1.0f / 1024.0f) - mu * mu, 0.0f);
  const float rs = rsqrtf(var + 1e-5f);
  f32x4 g4 = *(const f32x4*)&gm[t * 4];
  f32x4 b4 = *(const f32x4*)&bt[t * 4];
  f32x4 ov;
#pragma unroll
  for (int j = 0; j < 4; ++j) ov[j] = (v[j] - mu) * rs * g4[j] + b4[j];
  *(f32x4*)&outF[(size_t)row * 1024 + t * 4] = ov;
  if (WB) {
    s16x4 ob;
#pragma unroll
    for (int j = 0; j < 4; ++j) ob[j] = (short)f2bf(ov[j]);
    *(s16x4*)&outB[(size_t)row * 1024 + t * 4] = ob;
  }
}

// ---------------- mask tile summary: any() over 64x64 tiles ----------------
__global__ __launch_bounds__(256) void mask_summary(
    const u8* __restrict__ mask, u8* __restrict__ msum) {
  const int kt = blockIdx.x, qt = blockIdx.y, b = blockIdx.z;
  const int tid = threadIdx.x;
  __shared__ int any_flag;
  if (tid == 0) any_flag = 0;
  __syncthreads();
  const u8* base = mask + ((size_t)(b * 2048 + qt * 64 + (tid >> 2))) * 2048 + kt * 64 + (tid & 3) * 16;
  const u32x4 v = *(const u32x4*)base;
  if (v[0] | v[1] | v[2] | v[3]) any_flag = 1;
  __syncthreads();
  if (tid == 0) msum[((size_t)b * 32 + qt) * 32 + kt] = (u8)any_flag;
}

// ---------------- flash attention (LDS-staged, XCD-swizzled, zero-shuffle PV) ----------------
// QKV: [B*S, 3072] bf16 (Q cols 0..1023, K cols 1024..2047); VT: [B*H,64,S] bf16.
// Swapped QK^T (mfma(K,Q), K=32): lane (l4,l15) holds S^T[kv=16t+4*l4+j][q=l15].
// PV uses mfma_f32_16x16x16_bf16: acc layout == B-frag layout (k=4*l4+e, col=l15)
// -> P feeds PV with ZERO cross-lane exchange. Defer-max skips O-rescale (T13).
__global__ __launch_bounds__(256) void attn_k(
    const u16* __restrict__ QKV, const u16* __restrict__ VT,
    const u8* __restrict__ mask, const u8* __restrict__ msum, u16* __restrict__ out) {
  const int S = 2048, QSTR = 3072, Dm = 1024;
  const int wgid = blockIdx.x + gridDim.x * blockIdx.y;  // 0..1023
  const int xcd = wgid & 7, slot = wgid >> 3;
  const int bh = xcd * 4 + (slot >> 5);
  const int qt = slot & 31;
  const int b = bh >> 4, h = bh & 15;
  const int wave = threadIdx.x >> 6, lane = threadIdx.x & 63;
  const int l15 = lane & 15, l4 = lane >> 4;
  const int q0 = qt * 64 + wave * 16;
  const float CE = 0.125f * 1.44269504f;  // 1/sqrt(64) * log2(e)

  __shared__ __align__(16) u16 lK[2][4096];  // [buf][64 rows x 64 cols], XOR-swizzled
  __shared__ __align__(16) u16 lV[2][4096];

  const size_t qoff = (size_t)(b * S + q0 + l15) * QSTR + h * 64;
  const s16x8 qa0 = *(const s16x8*)&QKV[qoff + l4 * 8];
  const s16x8 qa1 = *(const s16x8*)&QKV[qoff + 32 + l4 * 8];

  f32x4 o[4] = {};
  float mr = -1e30f, lr = 0.0f;
  const u8* mb = mask + (size_t)b * S * S;
  const u8* msb = msum + (size_t)(b * 32 + qt) * 32;
  const u16* vbase = VT + (size_t)bh * 64 * S;
  const int bS = b * S;

  // stage K/VT 64x64 tiles; LDS dest linear, global source pre-swizzled:
  // LDS[row][cb] = G[row][cb ^ ((row&7)<<4)] (byte addressing).
  auto stage = [&](int bi, int kvv) {
#pragma unroll
    for (int c = 0; c < 2; ++c) {
      const int byt = ((c * 4 + wave) * 64 + lane) * 16;  // 0..8191
      const int row = byt >> 7;
      const int cb = (byt & 127) ^ ((row & 7) << 4);
      GLDS16(QKV + (size_t)(bS + kvv + row) * QSTR + 1024 + h * 64 + (cb >> 1),
             &lK[bi][(c * 4 + wave) * 512]);
      GLDS16(vbase + (size_t)row * S + kvv + (cb >> 1),
             &lV[bi][(c * 4 + wave) * 512]);
    }
  };

  stage(0, 0);
  __syncthreads();
  int buf = 0;

  for (int kv = 0; kv < S; kv += 64) {
    if (kv + 64 < S) stage(buf ^ 1, kv + 64);
    const char* kbuf = (const char*)&lK[buf][0];
    const char* vbuf = (const char*)&lV[buf][0];

    // ---- QK^T (swapped): sc[t] = mfma(K,Q) ----
    f32x4 sc[4];
    __builtin_amdgcn_s_setprio(1);
#pragma unroll
    for (int t = 0; t < 4; ++t) {
      const int row = t * 16 + l15;
      const int sw = (row & 7) << 4;
      const s16x8 kf0 = *(const s16x8*)(kbuf + row * 128 + ((l4 * 16) ^ sw));
      const s16x8 kf1 = *(const s16x8*)(kbuf + row * 128 + ((64 + l4 * 16) ^ sw));
      f32x4 z = {};
      z = __builtin_amdgcn_mfma_f32_16x16x32_bf16(kf0, qa0, z, 0, 0, 0);
      z = __builtin_amdgcn_mfma_f32_16x16x32_bf16(kf1, qa1, z, 0, 0, 0);
      sc[t] = z;
    }
    __builtin_amdgcn_s_setprio(0);
    // ---- mask (rare slow path via tile summary) ----
    if (msb[kv >> 6]) {
#pragma unroll
      for (int t = 0; t < 4; ++t) {
        const uchar4 m4 = *(const uchar4*)&mb[(size_t)(q0 + l15) * S + kv + t * 16 + l4 * 4];
        if (m4.x) sc[t][0] = -INFINITY;
        if (m4.y) sc[t][1] = -INFINITY;
        if (m4.z) sc[t][2] = -INFINITY;
        if (m4.w) sc[t][3] = -INFINITY;
      }
    }
    // ---- online softmax with defer-max (q = l15 in-register stats) ----
    float pm = sc[0][0];
#pragma unroll
    for (int t = 0; t < 4; ++t)
#pragma unroll
      for (int j = 0; j < 4; ++j) pm = fmaxf(pm, sc[t][j]);
    pm = fmaxf(pm, __shfl_xor(pm, 16));
    pm = fmaxf(pm, __shfl_xor(pm, 32));
    if (!__all(pm <= mr + 44.0f)) {  // 44 raw = 8 in exp2-units; p bounded by 2^8
      const float mn = fmaxf(mr, pm);
      const float al = exp2f((mr - mn) * CE);
      mr = mn;
      lr *= al;
#pragma unroll
      for (int n = 0; n < 4; ++n)
#pragma unroll
        for (int j = 0; j < 4; ++j) o[n][j] *= al;
    }
    float rsum = 0.0f;
#pragma unroll
    for (int t = 0; t < 4; ++t)
#pragma unroll
      for (int j = 0; j < 4; ++j) {
        const float p = exp2f((sc[t][j] - mr) * CE);
        sc[t][j] = p;
        rsum += p;
      }
    rsum += __shfl_xor(rsum, 16);
    rsum += __shfl_xor(rsum, 32);
    lr += rsum;
    // ---- pack P rows into B-frags of mfma_16x16x16 (zero cross-lane) ----
    s16x4 pb[4];
#pragma unroll
    for (int t = 0; t < 4; ++t) {
      const u32 lo = (u32)f2bf(sc[t][0]) | ((u32)f2bf(sc[t][1]) << 16);
      const u32 hi = (u32)f2bf(sc[t][2]) | ((u32)f2bf(sc[t][3]) << 16);
      pb[t] = __builtin_bit_cast(s16x4, u32x2{lo, hi});
    }
    // ---- PV: o[n] += mfma_16x16x16(V^T frag, P frag) over 4 kv-16 subtiles ----
    __builtin_amdgcn_s_setprio(1);
#pragma unroll
    for (int n = 0; n < 4; ++n) {
      const int row = n * 16 + l15;
      const int sw = (row & 7) << 4;
#pragma unroll
      for (int t = 0; t < 4; ++t) {
        const s16x4 va = *(const s16x4*)(vbuf + row * 128 + ((t * 32 + l4 * 8) ^ sw));
        o[n] = __builtin_amdgcn_mfma_f32_16x16x16bf16_1k(va, pb[t], o[n], 0, 0, 0);
      }
    }
    __builtin_amdgcn_s_setprio(0);
    __syncthreads();  // drains prefetch vmcnt + protects buf swap
    buf ^= 1;
  }
  // ---- epilogue ----
  const float inv = lr > 0.0f ? 1.0f / lr : 0.0f;
  const size_t obase = (size_t)(b * S + q0 + l15) * Dm + h * 64;
#pragma unroll
  for (int n = 0; n < 4; ++n) {
    s16x4 ov;
#pragma unroll
    for (int j = 0; j < 4; ++j) ov[j] = (short)f2bf(o[n][j] * inv);
    *(s16x4*)&out[obase + n * 16 + l4 * 4] = ov;
  }
}

extern "C" void kernel_launch(void* const* d_in, const int* in_sizes, int n_in,
                              void* d_out, int out_size, void* d_ws, size_t ws_size,
                              hipStream_t stream) {
  (void)in_sizes; (void)n_in; (void)out_size; (void)ws_size;
  const float* x = (const float*)d_in[0];
  const u8* mask = (const u8*)d_in[1];
  const float* Wq = (const float*)d_in[2];
  const float* Wk = (const float*)d_in[3];
  const float* Wv = (const float*)d_in[4];
  const float* Wo = (const float*)d_in[5];
  const float* bo = (const float*)d_in[6];
  const float* W1 = (const float*)d_in[7];
  const float* b1 = (const float*)d_in[8];
  const float* W2 = (const float*)d_in[9];
  const float* b2 = (const float*)d_in[10];
  const float* g1 = (const float*)d_in[11];
  const float* be1 = (const float*)d_in[12];
  const float* g2 = (const float*)d_in[13];
  const float* be2 = (const float*)d_in[14];
  float* outp = (float*)d_out;

  const int B = 2, S = 2048, D = 1024, FF = 4096;
  const int M = B * S;  // 4096
  char* w = (char*)d_ws;
  const size_t MB = 1024 * 1024;
  // workspace layout (peak 104 MB)
  u16* wqkvT = (u16*)(w + 0 * MB);    // [3072,1024] bf16   [0,6)
  u16* woT = (u16*)(w + 6 * MB);      // [1024,1024]        [6,8)
  u16* w1T = (u16*)(w + 8 * MB);      // [4096,1024]        [8,16)
  u16* w2T = (u16*)(w + 16 * MB);     // [1024,4096]        [16,24)
  u16* xb  = (u16*)(w + 24 * MB);     // [4096,1024]        [24,32)
  u16* qkv = (u16*)(w + 32 * MB);     // [4096,3072]        [32,56)
  u16* vt  = (u16*)(w + 56 * MB);     // [B*H,64,S]         [56,64)
  float* x0f = (float*)(w + 64 * MB); // [4096,1024] f32    [64,80)
  float* x1f = (float*)(w + 80 * MB); //                    [80,96)
  u16* x1b = (u16*)(w + 96 * MB);     // [4096,1024] bf16   [96,104)
  u8* msum = (u8*)(w + 64 * MB);      // 2 KB, dead before x0f is written
  u16* attn_o = xb;                   // xb dead after QKV gemm
  u16* ff1 = (u16*)(w + 32 * MB);     // [4096,4096] bf16, reuses qkv+vt [32,64)
  float* y0f = x0f;

  // weight prep (Wq/Wk/Wv transposed into one contiguous [3072,1024] block)
  transpose_f32_bf16<<<dim3(32, 32), 256, 0, stream>>>(Wq, wqkvT, 1024, 1024);
  transpose_f32_bf16<<<dim3(32, 32), 256, 0, stream>>>(Wk, wqkvT + 1024 * 1024, 1024, 1024);
  transpose_f32_bf16<<<dim3(32, 32), 256, 0, stream>>>(Wv, wqkvT + 2048 * 1024, 1024, 1024);
  transpose_f32_bf16<<<dim3(32, 32), 256, 0, stream>>>(Wo, woT, 1024, 1024);
  transpose_f32_bf16<<<dim3(128, 32), 256, 0, stream>>>(W1, w1T, 1024, 4096);
  transpose_f32_bf16<<<dim3(32, 128), 256, 0, stream>>>(W2, w2T, 4096, 1024);
  cvt_f32_bf16<<<dim3(M * D / 4 / 256), 256, 0, stream>>>(x, xb, M * D / 4);
  mask_summary<<<dim3(32, 32, 2), 256, 0, stream>>>(mask, msum);

  // fused QKV projection: [4096,1024] @ [3072,1024]^T -> [4096,3072]
  gemm_bt<0><<<dim3(3 * D / 128, M / 128), 256, 0, stream>>>(xb, wqkvT, M, 3 * D, D, nullptr, nullptr, qkv, nullptr);
  // V -> V^T per batch (strided read from qkv cols 2048..3071)
  transpose_bf16_b<<<dim3(32, 64, 2), 256, 0, stream>>>(qkv, vt, 2048, 1024, 3072, 2048);

  // attention
  attn_k<<<dim3(32, 32), 256, 0, stream>>>(qkv, vt, mask, msum, attn_o);

  // Wo projection + bias + residual(x)
  gemm_bt<2><<<dim3(D / 128, M / 128), 256, 0, stream>>>(attn_o, woT, M, D, D, bo, x, nullptr, x0f);
  layernorm_k<1><<<dim3(M), 256, 0, stream>>>(x0f, g1, be1, x1f, x1b);
  gemm_bt<1><<<dim3(FF / 128, M / 128), 256, 0, stream>>>(x1b, w1T, M, FF, D, b1, nullptr, ff1, nullptr);
  gemm_bt<2><<<dim3(D / 128, M / 128), 256, 0, stream>>>(ff1, w2T, M, D, FF, b2, x1f, nullptr, y0f);
  layernorm_k<0><<<dim3(M), 256, 0, stream>>>(y0f, g2, be2, outp, nullptr);
}

// Round 5
// 295.536 us; speedup vs baseline: 1.7078x; 1.0879x over previous
//
#include <hip/hip_runtime.h>
#include <math.h>

typedef unsigned short u16;
typedef unsigned char u8;
typedef unsigned int u32;
typedef __attribute__((ext_vector_type(4))) float f32x4;
typedef __attribute__((ext_vector_type(8))) short s16x8;
typedef __attribute__((ext_vector_type(4))) short s16x4;
typedef __attribute__((ext_vector_type(4))) u32 u32x4;
typedef __attribute__((ext_vector_type(2))) u32 u32x2;

__device__ __forceinline__ u16 f2bf(float f) {
  unsigned u = __builtin_bit_cast(unsigned, f);
  u += 0x7fffu + ((u >> 16) & 1u);
  return (u16)(u >> 16);
}

__device__ __forceinline__ u32 cvtpk_bf16(float lo, float hi) {
  u32 r;
  asm("v_cvt_pk_bf16_f32 %0, %1, %2" : "=v"(r) : "v"(lo), "v"(hi));
  return r;
}

__device__ __forceinline__ float max3f(float a, float b, float c) {
  return fmaxf(fmaxf(a, b), c);  // fuses to v_max3_f32
}

#define GLDS16(g, l) __builtin_amdgcn_global_load_lds( \
    (const __attribute__((address_space(1))) void*)(g), \
    (__attribute__((address_space(3))) void*)(l), 16, 0, 0)

// ---------------- GEMM: C[M,N] = A[M,K](bf16) @ BT[N,K](bf16)^T ----------------
// 2-phase double-buffered staging. BM=128 (4 row-tiles/wave) or BM=64 (2) --
// BM=64 doubles the grid for N=1024 shapes (2 blocks/CU -> cross-block overlap).
template <int EPI, int BM>
__global__ __launch_bounds__(256, 2) void gemm_bt(
    const u16* __restrict__ A, const u16* __restrict__ BT, int M, int N, int K,
    const float* __restrict__ bias, const float* __restrict__ resid,
    u16* __restrict__ outB, float* __restrict__ outF) {
  constexpr int MT = BM / 32;  // acc row-tiles per wave
  __shared__ __align__(16) u16 lA[2][BM * 32];
  __shared__ __align__(16) u16 lB[2][128 * 32];
  const int tid = threadIdx.x;
  const int wave = __builtin_amdgcn_readfirstlane(tid >> 6);
  const int lane = tid & 63;
  const int l15 = lane & 15, l4 = lane >> 4;
  const int wr = wave >> 1, wc = wave & 1;
  const int row0 = blockIdx.y * BM, col0 = blockIdx.x * 128;

  f32x4 acc[MT][4] = {};

  auto stage = [&](int bi, int k0) {
#pragma unroll
    for (int c = 0; c < BM / 64; ++c) {
      const int chunk = c * 4 + wave;          // 1KB chunks of A
      const int idx = chunk * 64 + lane;       // 16B-unit index
      const int r = idx >> 2, cb = (idx & 3) * 8;
      GLDS16(A + (size_t)(row0 + r) * K + k0 + cb, &lA[bi][chunk * 512]);
    }
#pragma unroll
    for (int c = 0; c < 2; ++c) {
      const int chunk = c * 4 + wave;
      const int idx = chunk * 64 + lane;
      const int r = idx >> 2, cb = (idx & 3) * 8;
      GLDS16(BT + (size_t)(col0 + r) * K + k0 + cb, &lB[bi][chunk * 512]);
    }
  };

  stage(0, 0);
  __syncthreads();
  int buf = 0;

  for (int k0 = 0; k0 < K; k0 += 32) {
    if (k0 + 32 < K) stage(buf ^ 1, k0 + 32);  // async prefetch, drained at loop-end barrier
    s16x8 af[MT], bfr[4];
#pragma unroll
    for (int m = 0; m < MT; ++m)
      af[m] = *(const s16x8*)&lA[buf][(wr * (BM / 2) + m * 16 + l15) * 32 + l4 * 8];
#pragma unroll
    for (int n = 0; n < 4; ++n)
      bfr[n] = *(const s16x8*)&lB[buf][(wc * 64 + n * 16 + l15) * 32 + l4 * 8];
#pragma unroll
    for (int m = 0; m < MT; ++m)
#pragma unroll
      for (int n = 0; n < 4; ++n)
        acc[m][n] = __builtin_amdgcn_mfma_f32_16x16x32_bf16(af[m], bfr[n], acc[m][n], 0, 0, 0);
    __syncthreads();
    buf ^= 1;
  }

#pragma unroll
  for (int m = 0; m < MT; ++m) {
    const int rowb = row0 + wr * (BM / 2) + m * 16 + l4 * 4;
#pragma unroll
    for (int n = 0; n < 4; ++n) {
      const int col = col0 + wc * 64 + n * 16 + l15;
#pragma unroll
      for (int j = 0; j < 4; ++j) {
        const int r = rowb + j;
        float v = acc[m][n][j];
        if (EPI == 0) {
          outB[(size_t)r * N + col] = f2bf(v);
        } else if (EPI == 1) {
          v += bias[col];
          outB[(size_t)r * N + col] = f2bf(v > 0.0f ? v : 0.0f);
        } else {
          v += bias[col] + resid[(size_t)r * N + col];
          outF[(size_t)r * N + col] = v;
        }
      }
    }
  }
}

// ---------------- weight transpose f32 -> bf16 ----------------
__global__ __launch_bounds__(256) void transpose_f32_bf16(
    const float* __restrict__ in, u16* __restrict__ out, int R, int C) {
  __shared__ float t[32][33];
  const int c0 = blockIdx.x * 32, r0 = blockIdx.y * 32;
  const int tx = threadIdx.x & 31, ty = threadIdx.x >> 5;
#pragma unroll
  for (int i = 0; i < 4; ++i)
    t[ty + i * 8][tx] = in[(size_t)(r0 + ty + i * 8) * C + c0 + tx];
  __syncthreads();
#pragma unroll
  for (int i = 0; i < 4; ++i)
    out[(size_t)(c0 + ty + i * 8) * R + r0 + tx] = f2bf(t[tx][ty + i * 8]);
}

// ---------------- batched bf16 transpose (strided input, col-offset) ----------------
__global__ __launch_bounds__(256) void transpose_bf16_b(
    const u16* __restrict__ in, u16* __restrict__ out, int R, int C, int rstr, int coff) {
  __shared__ u16 t[32][34];
  const int b = blockIdx.z;
  const u16* pi = in + (size_t)b * R * rstr + coff;
  u16* po = out + (size_t)b * R * C;
  const int c0 = blockIdx.x * 32, r0 = blockIdx.y * 32;
  const int tx = threadIdx.x & 31, ty = threadIdx.x >> 5;
#pragma unroll
  for (int i = 0; i < 4; ++i)
    t[ty + i * 8][tx] = pi[(size_t)(r0 + ty + i * 8) * rstr + c0 + tx];
  __syncthreads();
#pragma unroll
  for (int i = 0; i < 4; ++i)
    po[(size_t)(c0 + ty + i * 8) * R + r0 + tx] = t[tx][ty + i * 8];
}

// ---------------- f32 -> bf16 elementwise ----------------
__global__ __launch_bounds__(256) void cvt_f32_bf16(
    const float* __restrict__ in, u16* __restrict__ out, int n4) {
  const int i = blockIdx.x * 256 + threadIdx.x;
  if (i >= n4) return;
  f32x4 v = *(const f32x4*)&in[(size_t)i * 4];
  s16x4 o;
#pragma unroll
  for (int j = 0; j < 4; ++j) o[j] = (short)f2bf(v[j]);
  *(s16x4*)&out[(size_t)i * 4] = o;
}

// ---------------- LayerNorm over D=1024 ----------------
template <int WB>
__global__ __launch_bounds__(256) void layernorm_k(
    const float* __restrict__ in, const float* __restrict__ gm, const float* __restrict__ bt,
    float* __restrict__ outF, u16* __restrict__ outB) {
  const int row = blockIdx.x;
  const int t = threadIdx.x;
  const float* xr = in + (size_t)row * 1024;
  f32x4 v = *(const f32x4*)&xr[t * 4];
  float s = v[0] + v[1] + v[2] + v[3];
  float s2 = v[0] * v[0] + v[1] * v[1] + v[2] * v[2] + v[3] * v[3];
#pragma unroll
  for (int o = 32; o; o >>= 1) {
    s += __shfl_down(s, o);
    s2 += __shfl_down(s2, o);
  }
  __shared__ float red[8];
  const int lane = t & 63, wv = t >> 6;
  if (lane == 0) { red[wv] = s; red[4 + wv] = s2; }
  __syncthreads();
  s = red[0] + red[1] + red[2] + red[3];
  s2 = red[4] + red[5] + red[6] + red[7];
  const float mu = s * (1.0f / 1024.0f);
  const float var = fmaxf(s2 * (1.0f / 1024.0f) - mu * mu, 0.0f);
  const float rs = rsqrtf(var + 1e-5f);
  f32x4 g4 = *(const f32x4*)&gm[t * 4];
  f32x4 b4 = *(const f32x4*)&bt[t * 4];
  f32x4 ov;
#pragma unroll
  for (int j = 0; j < 4; ++j) ov[j] = (v[j] - mu) * rs * g4[j] + b4[j];
  *(f32x4*)&outF[(size_t)row * 1024 + t * 4] = ov;
  if (WB) {
    s16x4 ob;
#pragma unroll
    for (int j = 0; j < 4; ++j) ob[j] = (short)f2bf(ov[j]);
    *(s16x4*)&outB[(size_t)row * 1024 + t * 4] = ob;
  }
}

// ---------------- mask tile summary: any() over 64x64 tiles ----------------
__global__ __launch_bounds__(256) void mask_summary(
    const u8* __restrict__ mask, u8* __restrict__ msum) {
  const int kt = blockIdx.x, qt = blockIdx.y, b = blockIdx.z;
  const int tid = threadIdx.x;
  __shared__ int any_flag;
  if (tid == 0) any_flag = 0;
  __syncthreads();
  const u8* base = mask + ((size_t)(b * 2048 + qt * 64 + (tid >> 2))) * 2048 + kt * 64 + (tid & 3) * 16;
  const u32x4 v = *(const u32x4*)base;
  if (v[0] | v[1] | v[2] | v[3]) any_flag = 1;
  __syncthreads();
  if (tid == 0) msum[((size_t)b * 32 + qt) * 32 + kt] = (u8)any_flag;
}

// ---------------- flash attention (LDS-staged, XCD-swizzled, zero-shuffle PV) ----------------
// QKV: [B*S, 3072] bf16 (Q cols 0..1023, K cols 1024..2047); VT: [B*H,64,S] bf16.
// Swapped QK^T (mfma(K,Q), K=32): lane (l4,l15) holds S^T[kv=16t+4*l4+j][q=l15].
// PV uses mfma_f32_16x16x16_bf16: acc layout == B-frag layout -> zero cross-lane P move.
__global__ __launch_bounds__(256) void attn_k(
    const u16* __restrict__ QKV, const u16* __restrict__ VT,
    const u8* __restrict__ mask, const u8* __restrict__ msum, u16* __restrict__ out) {
  const int S = 2048, QSTR = 3072, Dm = 1024;
  const int wgid = blockIdx.x + gridDim.x * blockIdx.y;  // 0..1023
  const int xcd = wgid & 7, slot = wgid >> 3;
  const int bh = xcd * 4 + (slot >> 5);
  const int qt = slot & 31;
  const int b = bh >> 4, h = bh & 15;
  const int wave = threadIdx.x >> 6, lane = threadIdx.x & 63;
  const int l15 = lane & 15, l4 = lane >> 4;
  const int q0 = qt * 64 + wave * 16;
  const float CE = 0.125f * 1.44269504f;  // 1/sqrt(64) * log2(e)

  __shared__ __align__(16) u16 lK[2][4096];  // [buf][64 rows x 64 cols], XOR-swizzled
  __shared__ __align__(16) u16 lV[2][4096];

  const size_t qoff = (size_t)(b * S + q0 + l15) * QSTR + h * 64;
  const s16x8 qa0 = *(const s16x8*)&QKV[qoff + l4 * 8];
  const s16x8 qa1 = *(const s16x8*)&QKV[qoff + 32 + l4 * 8];

  f32x4 o[4] = {};
  float mr = -1e30f, lr = 0.0f;
  const u8* mb = mask + (size_t)b * S * S;
  const u8* msb = msum + (size_t)(b * 32 + qt) * 32;
  const u16* vbase = VT + (size_t)bh * 64 * S;
  const int bS = b * S;

  auto stage = [&](int bi, int kvv) {
#pragma unroll
    for (int c = 0; c < 2; ++c) {
      const int byt = ((c * 4 + wave) * 64 + lane) * 16;  // 0..8191
      const int row = byt >> 7;
      const int cb = (byt & 127) ^ ((row & 7) << 4);
      GLDS16(QKV + (size_t)(bS + kvv + row) * QSTR + 1024 + h * 64 + (cb >> 1),
             &lK[bi][(c * 4 + wave) * 512]);
      GLDS16(vbase + (size_t)row * S + kvv + (cb >> 1),
             &lV[bi][(c * 4 + wave) * 512]);
    }
  };

  stage(0, 0);
  __syncthreads();
  int buf = 0;

  for (int kv = 0; kv < S; kv += 64) {
    if (kv + 64 < S) stage(buf ^ 1, kv + 64);
    const char* kbuf = (const char*)&lK[buf][0];
    const char* vbuf = (const char*)&lV[buf][0];

    // ---- QK^T (swapped): sc[t] = mfma(K,Q) ----
    f32x4 sc[4];
    __builtin_amdgcn_s_setprio(1);
#pragma unroll
    for (int t = 0; t < 4; ++t) {
      const int row = t * 16 + l15;
      const int sw = (row & 7) << 4;
      const s16x8 kf0 = *(const s16x8*)(kbuf + row * 128 + ((l4 * 16) ^ sw));
      const s16x8 kf1 = *(const s16x8*)(kbuf + row * 128 + ((64 + l4 * 16) ^ sw));
      f32x4 z = {};
      z = __builtin_amdgcn_mfma_f32_16x16x32_bf16(kf0, qa0, z, 0, 0, 0);
      z = __builtin_amdgcn_mfma_f32_16x16x32_bf16(kf1, qa1, z, 0, 0, 0);
      sc[t] = z;
    }
    __builtin_amdgcn_s_setprio(0);
    // ---- mask (rare slow path via tile summary) ----
    if (msb[kv >> 6]) {
#pragma unroll
      for (int t = 0; t < 4; ++t) {
        const uchar4 m4 = *(const uchar4*)&mb[(size_t)(q0 + l15) * S + kv + t * 16 + l4 * 4];
        if (m4.x) sc[t][0] = -INFINITY;
        if (m4.y) sc[t][1] = -INFINITY;
        if (m4.z) sc[t][2] = -INFINITY;
        if (m4.w) sc[t][3] = -INFINITY;
      }
    }
    // ---- online softmax with defer-max; max via v_max3 tree ----
    float pm = max3f(sc[0][0], sc[0][1], sc[0][2]);
    pm = max3f(pm, sc[0][3], sc[1][0]);
    pm = max3f(pm, sc[1][1], sc[1][2]);
    pm = max3f(pm, sc[1][3], sc[2][0]);
    pm = max3f(pm, sc[2][1], sc[2][2]);
    pm = max3f(pm, sc[2][3], sc[3][0]);
    pm = max3f(pm, sc[3][1], sc[3][2]);
    pm = fmaxf(pm, sc[3][3]);
    pm = fmaxf(pm, __shfl_xor(pm, 16));
    pm = fmaxf(pm, __shfl_xor(pm, 32));
    if (!__all(pm <= mr + 44.0f)) {  // 44 raw = 8 exp2-units; p bounded by 2^8
      const float mn = fmaxf(mr, pm);
      const float al = exp2f((mr - mn) * CE);
      mr = mn;
      lr *= al;
#pragma unroll
      for (int n = 0; n < 4; ++n)
#pragma unroll
        for (int j = 0; j < 4; ++j) o[n][j] *= al;
    }
    const float mrc = mr * CE;
    float rsum = 0.0f;
#pragma unroll
    for (int t = 0; t < 4; ++t)
#pragma unroll
      for (int j = 0; j < 4; ++j) {
        const float p = exp2f(fmaf(sc[t][j], CE, -mrc));
        sc[t][j] = p;
        rsum += p;
      }
    rsum += __shfl_xor(rsum, 16);
    rsum += __shfl_xor(rsum, 32);
    lr += rsum;
    // ---- pack P into 16x16x16 B-frags via v_cvt_pk_bf16_f32 (1 inst/pair) ----
    s16x4 pb[4];
#pragma unroll
    for (int t = 0; t < 4; ++t) {
      const u32 lo = cvtpk_bf16(sc[t][0], sc[t][1]);
      const u32 hi = cvtpk_bf16(sc[t][2], sc[t][3]);
      pb[t] = __builtin_bit_cast(s16x4, u32x2{lo, hi});
    }
    // ---- PV: o[n] += mfma_16x16x16(V^T frag, P frag) over 4 kv-16 subtiles ----
    __builtin_amdgcn_s_setprio(1);
#pragma unroll
    for (int n = 0; n < 4; ++n) {
      const int row = n * 16 + l15;
      const int sw = (row & 7) << 4;
#pragma unroll
      for (int t = 0; t < 4; ++t) {
        const s16x4 va = *(const s16x4*)(vbuf + row * 128 + ((t * 32 + l4 * 8) ^ sw));
        o[n] = __builtin_amdgcn_mfma_f32_16x16x16bf16_1k(va, pb[t], o[n], 0, 0, 0);
      }
    }
    __builtin_amdgcn_s_setprio(0);
    __syncthreads();  // drains prefetch vmcnt + protects buf swap
    buf ^= 1;
  }
  // ---- epilogue (cvt_pk pack) ----
  const float inv = lr > 0.0f ? 1.0f / lr : 0.0f;
  const size_t obase = (size_t)(b * S + q0 + l15) * Dm + h * 64;
#pragma unroll
  for (int n = 0; n < 4; ++n) {
    const u32 lo = cvtpk_bf16(o[n][0] * inv, o[n][1] * inv);
    const u32 hi = cvtpk_bf16(o[n][2] * inv, o[n][3] * inv);
    *(u32x2*)&out[obase + n * 16 + l4 * 4] = u32x2{lo, hi};
  }
}

extern "C" void kernel_launch(void* const* d_in, const int* in_sizes, int n_in,
                              void* d_out, int out_size, void* d_ws, size_t ws_size,
                              hipStream_t stream) {
  (void)in_sizes; (void)n_in; (void)out_size; (void)ws_size;
  const float* x = (const float*)d_in[0];
  const u8* mask = (const u8*)d_in[1];
  const float* Wq = (const float*)d_in[2];
  const float* Wk = (const float*)d_in[3];
  const float* Wv = (const float*)d_in[4];
  const float* Wo = (const float*)d_in[5];
  const float* bo = (const float*)d_in[6];
  const float* W1 = (const float*)d_in[7];
  const float* b1 = (const float*)d_in[8];
  const float* W2 = (const float*)d_in[9];
  const float* b2 = (const float*)d_in[10];
  const float* g1 = (const float*)d_in[11];
  const float* be1 = (const float*)d_in[12];
  const float* g2 = (const float*)d_in[13];
  const float* be2 = (const float*)d_in[14];
  float* outp = (float*)d_out;

  const int B = 2, S = 2048, D = 1024, FF = 4096;
  const int M = B * S;  // 4096
  char* w = (char*)d_ws;
  const size_t MB = 1024 * 1024;
  u16* wqkvT = (u16*)(w + 0 * MB);    // [3072,1024] bf16   [0,6)
  u16* woT = (u16*)(w + 6 * MB);      // [1024,1024]        [6,8)
  u16* w1T = (u16*)(w + 8 * MB);      // [4096,1024]        [8,16)
  u16* w2T = (u16*)(w + 16 * MB);     // [1024,4096]        [16,24)
  u16* xb  = (u16*)(w + 24 * MB);     // [4096,1024]        [24,32)
  u16* qkv = (u16*)(w + 32 * MB);     // [4096,3072]        [32,56)
  u16* vt  = (u16*)(w + 56 * MB);     // [B*H,64,S]         [56,64)
  float* x0f = (float*)(w + 64 * MB); // [4096,1024] f32    [64,80)
  float* x1f = (float*)(w + 80 * MB); //                    [80,96)
  u16* x1b = (u16*)(w + 96 * MB);     // [4096,1024] bf16   [96,104)
  u8* msum = (u8*)(w + 64 * MB);      // 2 KB, dead before x0f is written
  u16* attn_o = xb;                   // xb dead after QKV gemm
  u16* ff1 = (u16*)(w + 32 * MB);     // [4096,4096] bf16, reuses qkv+vt [32,64)
  float* y0f = x0f;

  // weight prep (Wq/Wk/Wv transposed into one contiguous [3072,1024] block)
  transpose_f32_bf16<<<dim3(32, 32), 256, 0, stream>>>(Wq, wqkvT, 1024, 1024);
  transpose_f32_bf16<<<dim3(32, 32), 256, 0, stream>>>(Wk, wqkvT + 1024 * 1024, 1024, 1024);
  transpose_f32_bf16<<<dim3(32, 32), 256, 0, stream>>>(Wv, wqkvT + 2048 * 1024, 1024, 1024);
  transpose_f32_bf16<<<dim3(32, 32), 256, 0, stream>>>(Wo, woT, 1024, 1024);
  transpose_f32_bf16<<<dim3(128, 32), 256, 0, stream>>>(W1, w1T, 1024, 4096);
  transpose_f32_bf16<<<dim3(32, 128), 256, 0, stream>>>(W2, w2T, 4096, 1024);
  cvt_f32_bf16<<<dim3(M * D / 4 / 256), 256, 0, stream>>>(x, xb, M * D / 4);
  mask_summary<<<dim3(32, 32, 2), 256, 0, stream>>>(mask, msum);

  // fused QKV projection: [4096,1024] @ [3072,1024]^T -> [4096,3072]
  gemm_bt<0, 128><<<dim3(3 * D / 128, M / 128), 256, 0, stream>>>(xb, wqkvT, M, 3 * D, D, nullptr, nullptr, qkv, nullptr);
  // V -> V^T per batch (strided read from qkv cols 2048..3071)
  transpose_bf16_b<<<dim3(32, 64, 2), 256, 0, stream>>>(qkv, vt, 2048, 1024, 3072, 2048);

  // attention
  attn_k<<<dim3(32, 32), 256, 0, stream>>>(qkv, vt, mask, msum, attn_o);

  // Wo projection + bias + residual(x) -- BM=64 for 2 blocks/CU
  gemm_bt<2, 64><<<dim3(D / 128, M / 64), 256, 0, stream>>>(attn_o, woT, M, D, D, bo, x, nullptr, x0f);
  layernorm_k<1><<<dim3(M), 256, 0, stream>>>(x0f, g1, be1, x1f, x1b);
  gemm_bt<1, 128><<<dim3(FF / 128, M / 128), 256, 0, stream>>>(x1b, w1T, M, FF, D, b1, nullptr, ff1, nullptr);
  gemm_bt<2, 64><<<dim3(D / 128, M / 64), 256, 0, stream>>>(ff1, w2T, M, D, FF, b2, x1f, nullptr, y0f);
  layernorm_k<0><<<dim3(M), 256, 0, stream>>>(y0f, g2, be2, outp, nullptr);
}